// Round 5
// baseline (193.126 us; speedup 1.0000x reference)
//
#include <hip/hip_runtime.h>
#include <hip/hip_bf16.h>
#include <stdint.h>

using bf16 = __hip_bfloat16;
typedef __bf16 bf16x8 __attribute__((ext_vector_type(8)));
typedef float f32x4 __attribute__((ext_vector_type(4)));
typedef unsigned short u16x8 __attribute__((ext_vector_type(8)));
typedef unsigned short u16x4 __attribute__((ext_vector_type(4)));

#define AS1 __attribute__((address_space(1)))
#define AS3 __attribute__((address_space(3)))

__device__ inline unsigned short f2b(float f) {
    union { __hip_bfloat16 h; unsigned short u; } cv;
    cv.h = __float2bfloat16(f);
    return cv.u;
}

// ---------------- fp32 -> bf16 converts ----------------
__global__ __launch_bounds__(256) void cvt_pair(const float* __restrict__ a, const float* __restrict__ b,
                                                u16x8* __restrict__ oa, u16x8* __restrict__ ob, long n8) {
    const float* in = blockIdx.y ? b : a;
    u16x8* out = blockIdx.y ? ob : oa;
    long i = (long)blockIdx.x * blockDim.x + threadIdx.x;
    const long stride = (long)gridDim.x * blockDim.x;
    const float4* in4 = (const float4*)in;
    for (; i < n8; i += stride) {
        float4 x = in4[2 * i], y = in4[2 * i + 1];
        u16x8 o;
        o[0] = f2b(x.x); o[1] = f2b(x.y); o[2] = f2b(x.z); o[3] = f2b(x.w);
        o[4] = f2b(y.x); o[5] = f2b(y.y); o[6] = f2b(y.z); o[7] = f2b(y.w);
        out[i] = o;
    }
}

__global__ __launch_bounds__(256) void cvt_quad(const float* __restrict__ a, const float* __restrict__ b,
                                                const float* __restrict__ c, const float* __restrict__ d,
                                                u16x8* __restrict__ oa, u16x8* __restrict__ ob,
                                                u16x8* __restrict__ oc, u16x8* __restrict__ od, long n8) {
    const int y = blockIdx.y;
    const float* in = y == 0 ? a : (y == 1 ? b : (y == 2 ? c : d));
    u16x8* out = y == 0 ? oa : (y == 1 ? ob : (y == 2 ? oc : od));
    long i = (long)blockIdx.x * blockDim.x + threadIdx.x;
    const long stride = (long)gridDim.x * blockDim.x;
    const float4* in4 = (const float4*)in;
    for (; i < n8; i += stride) {
        float4 x = in4[2 * i], z = in4[2 * i + 1];
        u16x8 o;
        o[0] = f2b(x.x); o[1] = f2b(x.y); o[2] = f2b(x.z); o[3] = f2b(x.w);
        o[4] = f2b(z.x); o[5] = f2b(z.y); o[6] = f2b(z.z); o[7] = f2b(z.w);
        out[i] = o;
    }
}

template <typename T> __device__ inline void storev(T* p, float v);
template <> __device__ inline void storev<float>(float* p, float v) { *p = v; }
template <> __device__ inline void storev<bf16>(bf16* p, float v) { *p = __float2bfloat16(v); }

// ================= tiled GEMM: C = A(MxK) * B^T(NxK) =================
// BN=256: 256x256 tile, 8 waves 2Mx4N (per-wave 128x64), 4-phase (32 MFMA each),
//         LDS 128KB. BN=128: 256x128 tile, 8 waves 4Mx2N, 4-phase, LDS 96KB.
// Double-buffered, counted vmcnt across barriers, XOR-swizzled LDS
// (linear gload_lds dest + inverse-swizzled global src + swizzled read),
// counted lgkmcnt split-waits.
// MODE 0: fused K|V projections   MODE 1: fused Q | V'=V@Wp^T (seg1 -> V'T)
// MODE 2: causal scores           MODE 3: PV -> final out (fp32)+bias, k-limit
template <typename OutT, int MODE, int BN>
__global__ __launch_bounds__(512, 2) void gemmX(
    const bf16* __restrict__ A0, const bf16* __restrict__ A1,
    const bf16* __restrict__ B0p, const bf16* __restrict__ B1p,
    OutT* __restrict__ C0, OutT* __restrict__ C1,
    const float* __restrict__ bias0, const float* __restrict__ bias1,
    float scale, int lda, int ldb, int ldc, int Kdim,
    long sA, long sB, long sC)
{
    constexpr int LDSZ = (BN == 256) ? 131072 : 98304;
    constexpr int BUFS = (BN == 256) ? 65536 : 49152;
    __shared__ __align__(16) char lds[LDSZ];

    // ---- block decode with XCD swizzle (all grids %8 == 0)
    const int nwg = gridDim.x;
    const int bid = blockIdx.x;
    const int s = (nwg & 7) ? bid : ((bid & 7) * (nwg >> 3) + (bid >> 3));

    int bm, ccol0, rowB0, seg = 0;
    const bf16 *A, *B;
    OutT* C;
    const float* bias = nullptr;

    if constexpr (MODE == 0) {                 // K|V: 256 = 32bm x 8bn
        bm = s >> 3; const int bnl = s & 7; seg = bnl >> 2;
        A = A0; B = B0p; rowB0 = bnl * 256;
        C = seg ? C1 : C0; bias = seg ? bias1 : bias0;
        ccol0 = (bnl & 3) * 256;
    } else if constexpr (MODE == 1) {          // Q | VWp: 256 = 2seg x 32bm x 4bn
        seg = s >> 7; const int r = s & 127; bm = r >> 2; const int bn = r & 3;
        A = seg ? A1 : A0; B = seg ? B1p : B0p;
        C = seg ? C1 : C0; bias = seg ? nullptr : bias0;
        rowB0 = bn * 256; ccol0 = bn * 256;
    } else if constexpr (MODE == 2) {          // scores: 144 = 4z x 36tri
        const int z = s / 36, f = s % 36;
        int m = 0;
        while ((m + 1) * (m + 2) / 2 <= f) ++m;
        bm = m; const int bn = f - m * (m + 1) / 2;
        A = A0 + (long)z * sA; B = B0p + (long)z * sB; C = C0 + (long)z * sC;
        rowB0 = bn * 256; ccol0 = bn * 256;
    } else {                                   // PV: 256 = 4z x 8bm x 8bn
        const int z = s >> 6, r = s & 63; bm = r >> 3; const int bn = r & 7;
        A = A0 + (long)z * sA; B = B0p + (long)z * sB; C = C0 + (long)z * sC;
        rowB0 = bn * 128; ccol0 = bn * 128; bias = bias0;
    }

    int KT = Kdim >> 6;
    if constexpr (MODE == 3) { const int lim = 4 * (bm + 1); if (lim < KT) KT = lim; }
    const int NIT = KT >> 1;

    const int tid = threadIdx.x;
    const int lane = tid & 63;
    const int w = tid >> 6;
    constexpr int WR = (BN == 256) ? 128 : 64;
    const int wm = (BN == 256) ? (w >> 2) : (w >> 1);
    const int wn = (BN == 256) ? (w & 3) : (w & 1);

    const int rowA0 = bm * 256;

    // ---- staging (linear LDS dest, inverse-swizzled global source)
    const int rr  = tid >> 3;
    const int lch = (tid & 7) ^ (rr & 7);
    const bf16* gAt = A + (long)(rowA0 + rr) * lda + lch * 8;
    const bf16* gBt = B + (long)(rowB0 + rr) * ldb + lch * 8;

#define LA(b) (lds + (b) * BUFS)
#define LB(b) (lds + 32768 + (b) * BUFS)

    auto SG2 = [&](const bf16* g, int ld, char* dst) {
        __builtin_amdgcn_global_load_lds((const AS1 void*)g,
            (AS3 void*)(dst + tid * 16), 16, 0, 0);
        __builtin_amdgcn_global_load_lds((const AS1 void*)(g + (long)64 * ld),
            (AS3 void*)(dst + 8192 + tid * 16), 16, 0, 0);
    };
    auto ST_A = [&](int kt, int half, int b) {
        SG2(gAt + (long)kt * 64 + (long)half * 128 * lda, lda, LA(b) + half * 16384);
    };
    auto ST_B = [&](int kt, int half, int b) {   // BN=256 halves
        SG2(gBt + (long)kt * 64 + (long)half * 128 * ldb, ldb, LB(b) + half * 16384);
    };
    auto ST_B1 = [&](int kt, int b) {            // BN=128 full B tile
        SG2(gBt + (long)kt * 64, ldb, LB(b));
    };

    // ---- swizzled fragment read addressing
    const int abase = (wm * WR + (lane & 15)) * 128;
    const int bbase = (wn * 64 + (lane & 15)) * 128;
    const int cc0 = (((lane >> 4) << 4)) ^ ((lane & 7) << 4);
    const int cc1 = cc0 ^ 64;

#define RAF(b, mh, mi, kk) (*(const bf16x8*)(LA(b) + abase + (mh)*8192 + (mi)*2048 + ((kk) ? cc1 : cc0)))
#define RBF(b, ni, kk)     (*(const bf16x8*)(LB(b) + bbase + (ni)*2048 + ((kk) ? cc1 : cc0)))

    f32x4 acc[(BN == 256) ? 8 : 4][4] = {};
    bf16x8 ar[4][2], blo[2][2], bhi[2][2];

#define RD_A2(b, mh, MI0) { ar[MI0][0] = RAF(b, mh, MI0, 0); ar[MI0][1] = RAF(b, mh, MI0, 1); \
                            ar[(MI0)+1][0] = RAF(b, mh, (MI0)+1, 0); ar[(MI0)+1][1] = RAF(b, mh, (MI0)+1, 1); }
#define RD_BLO(b)   { blo[0][0] = RBF(b, 0, 0); blo[0][1] = RBF(b, 0, 1); blo[1][0] = RBF(b, 1, 0); blo[1][1] = RBF(b, 1, 1); }
#define RD_BHI(b)   { bhi[0][0] = RBF(b, 2, 0); bhi[0][1] = RBF(b, 2, 1); bhi[1][0] = RBF(b, 3, 0); bhi[1][1] = RBF(b, 3, 1); }

#define MQ1(MI, bb, MH, NB) { \
    f32x4 t0_ = acc[(MH)*4 + (MI)][(NB)]; \
    t0_ = __builtin_amdgcn_mfma_f32_16x16x32_bf16(ar[MI][0], bb[0][0], t0_, 0, 0, 0); \
    t0_ = __builtin_amdgcn_mfma_f32_16x16x32_bf16(ar[MI][1], bb[0][1], t0_, 0, 0, 0); \
    acc[(MH)*4 + (MI)][(NB)] = t0_; \
    f32x4 t1_ = acc[(MH)*4 + (MI)][(NB) + 1]; \
    t1_ = __builtin_amdgcn_mfma_f32_16x16x32_bf16(ar[MI][0], bb[1][0], t1_, 0, 0, 0); \
    t1_ = __builtin_amdgcn_mfma_f32_16x16x32_bf16(ar[MI][1], bb[1][1], t1_, 0, 0, 0); \
    acc[(MH)*4 + (MI)][(NB) + 1] = t1_; }

#define WAIT_LGKM0 { asm volatile("s_waitcnt lgkmcnt(0)" ::: "memory"); __builtin_amdgcn_sched_barrier(0); }
#define WAIT_LGKM4 { asm volatile("s_waitcnt lgkmcnt(4)" ::: "memory"); __builtin_amdgcn_sched_barrier(0); }
#define WAIT_LGKM8 { asm volatile("s_waitcnt lgkmcnt(8)" ::: "memory"); __builtin_amdgcn_sched_barrier(0); }
#define SCHEDB     __builtin_amdgcn_sched_barrier(0)

    auto BAR = [&]() { __builtin_amdgcn_s_barrier(); SCHEDB; };
    auto PRIO1 = [&]() { __builtin_amdgcn_s_setprio(1); };
    auto PRIO0 = [&]() { __builtin_amdgcn_s_setprio(0); };

    if constexpr (BN == 256) {
        // ---- prologue: tile0 full -> buf0 (8 loads), tile1 B -> buf1 (4);
        // vmcnt(4) retires tile0, leaves B(t1)=4 outstanding (steady entry).
        ST_A(0, 0, 0); ST_A(0, 1, 0); ST_B(0, 0, 0); ST_B(0, 1, 0);
        ST_B(1, 0, 1); ST_B(1, 1, 1);
        asm volatile("s_waitcnt vmcnt(4)" ::: "memory");
        BAR();

        // 4 phases/iter; ledger (loads): entry B(t1)=4; A:+4(SA t1->b1)=8;
        // B:+4(SB t2->b0)=12, vmcnt(4) retires B(t1)+A(t1); C:+4(SA t2->b0)=8;
        // D:+4(SB t3->b1)=12, vmcnt(4) retires tile t2 -> steady 4.
        // Stage-safety: each stage issued after the end-barrier of the phase
        // holding the region's last ds_read (A(t1)->b1A after prev-D;
        // B(t2)->b0B after A; A(t2)->b0A after B; B(t3)->b1B after C).
        for (int i = 0; i < NIT; ++i) {
            const int t0 = 2 * i;
            const bool last = (i == NIT - 1);

            // Phase A: t0 (b0) mh0 x all n
            RD_BLO(0); RD_A2(0, 0, 0); SCHEDB; RD_A2(0, 0, 2); RD_BHI(0);
            ST_A(t0 + 1, 0, 1); ST_A(t0 + 1, 1, 1);
            BAR(); WAIT_LGKM8; PRIO1();
            MQ1(0, blo, 0, 0); MQ1(1, blo, 0, 0);
            WAIT_LGKM0;
            MQ1(2, blo, 0, 0); MQ1(3, blo, 0, 0);
            MQ1(0, bhi, 0, 2); MQ1(1, bhi, 0, 2); MQ1(2, bhi, 0, 2); MQ1(3, bhi, 0, 2);
            PRIO0(); BAR();

            // Phase B: t0 mh1 x all n; retire tile t0+1
            RD_A2(0, 1, 0); SCHEDB; RD_A2(0, 1, 2);
            if (!last) { ST_B(t0 + 2, 0, 0); ST_B(t0 + 2, 1, 0);
                         asm volatile("s_waitcnt vmcnt(4)" ::: "memory"); }
            else       { asm volatile("s_waitcnt vmcnt(0)" ::: "memory"); }
            BAR(); WAIT_LGKM4; PRIO1();
            MQ1(0, bhi, 1, 2); MQ1(1, bhi, 1, 2);
            WAIT_LGKM0;
            MQ1(2, bhi, 1, 2); MQ1(3, bhi, 1, 2);
            MQ1(0, blo, 1, 0); MQ1(1, blo, 1, 0); MQ1(2, blo, 1, 0); MQ1(3, blo, 1, 0);
            PRIO0(); BAR();

            // Phase C: t0+1 (b1) mh0 x all n
            RD_BLO(1); RD_A2(1, 0, 0); SCHEDB; RD_A2(1, 0, 2); RD_BHI(1);
            if (!last) { ST_A(t0 + 2, 0, 0); ST_A(t0 + 2, 1, 0); }
            BAR(); WAIT_LGKM8; PRIO1();
            MQ1(0, blo, 0, 0); MQ1(1, blo, 0, 0);
            WAIT_LGKM0;
            MQ1(2, blo, 0, 0); MQ1(3, blo, 0, 0);
            MQ1(0, bhi, 0, 2); MQ1(1, bhi, 0, 2); MQ1(2, bhi, 0, 2); MQ1(3, bhi, 0, 2);
            PRIO0(); BAR();

            // Phase D: t0+1 mh1 x all n; retire tile t0+2
            RD_A2(1, 1, 0); SCHEDB; RD_A2(1, 1, 2);
            if (!last) { ST_B(t0 + 3, 0, 1); ST_B(t0 + 3, 1, 1);
                         asm volatile("s_waitcnt vmcnt(4)" ::: "memory"); }
            BAR(); WAIT_LGKM4; PRIO1();
            MQ1(0, bhi, 1, 2); MQ1(1, bhi, 1, 2);
            WAIT_LGKM0;
            MQ1(2, bhi, 1, 2); MQ1(3, bhi, 1, 2);
            MQ1(0, blo, 1, 0); MQ1(1, blo, 1, 0); MQ1(2, blo, 1, 0); MQ1(3, blo, 1, 0);
            PRIO0(); BAR();
        }
    } else {
        // ---- BN=128 4-phase (unchanged from r4). Prologue: tiles 0,1 full.
        ST_A(0, 0, 0); ST_A(0, 1, 0); ST_B1(0, 0);
        ST_A(1, 0, 1); ST_A(1, 1, 1); ST_B1(1, 1);
        asm volatile("s_waitcnt vmcnt(6)" ::: "memory");
        BAR();

        for (int i = 0; i < NIT; ++i) {
            const int t0 = 2 * i;
            const bool last = (i == NIT - 1);

            RD_BLO(0); RD_A2(0, 0, 0); RD_A2(0, 0, 2); SCHEDB; RD_BHI(0);
            BAR(); WAIT_LGKM4; PRIO1();
            MQ1(0, blo, 0, 0); MQ1(1, blo, 0, 0); MQ1(2, blo, 0, 0); MQ1(3, blo, 0, 0);
            PRIO0(); BAR();

            if (!last) { ST_A(t0 + 2, 0, 0); ST_A(t0 + 2, 1, 0);
                         asm volatile("s_waitcnt vmcnt(4)" ::: "memory"); }
            else       { asm volatile("s_waitcnt vmcnt(0)" ::: "memory"); }
            BAR(); WAIT_LGKM0; PRIO1();
            MQ1(0, bhi, 0, 2); MQ1(1, bhi, 0, 2); MQ1(2, bhi, 0, 2); MQ1(3, bhi, 0, 2);
            PRIO0(); BAR();

            RD_BLO(1); RD_A2(1, 0, 0); RD_A2(1, 0, 2); SCHEDB; RD_BHI(1);
            if (!last) ST_B1(t0 + 2, 0);
            BAR(); WAIT_LGKM4; PRIO1();
            MQ1(0, blo, 0, 0); MQ1(1, blo, 0, 0); MQ1(2, blo, 0, 0); MQ1(3, blo, 0, 0);
            PRIO0(); BAR();

            if (!last) { ST_A(t0 + 3, 0, 1); ST_A(t0 + 3, 1, 1); ST_B1(t0 + 3, 1);
                         asm volatile("s_waitcnt vmcnt(6)" ::: "memory"); }
            BAR(); WAIT_LGKM0; PRIO1();
            MQ1(0, bhi, 0, 2); MQ1(1, bhi, 0, 2); MQ1(2, bhi, 0, 2); MQ1(3, bhi, 0, 2);
            PRIO0(); BAR();
        }
    }

    // ---- epilogue: C/D layout col=lane&15, row=(lane>>4)*4+j
    constexpr int MF = (BN == 256) ? 8 : 4;
    if (MODE == 1 && seg == 1) {
        // V'T per batch via per-wave LDS transpose (private 16KB region, free
        // after main loop's final barrier). Write [cl][rl^sw] bf16, read back
        // col-major, store 256B contiguous per column (full 64B lines).
        char* tw = lds + w * 16384;
#pragma unroll
        for (int ni = 0; ni < 4; ++ni) {
            const int cl = ni * 16 + (lane & 15);
            const int sw = 8 * (cl & 7);
#pragma unroll
            for (int mi = 0; mi < 8; ++mi) {
                const int rlb = mi * 16 + ((lane >> 4) << 2);
                u16x4 o;
                o[0] = f2b(acc[mi][ni][0]); o[1] = f2b(acc[mi][ni][1]);
                o[2] = f2b(acc[mi][ni][2]); o[3] = f2b(acc[mi][ni][3]);
                *(u16x4*)(tw + cl * 256 + 2 * (rlb ^ sw)) = o;
            }
        }
        asm volatile("s_waitcnt lgkmcnt(0)" ::: "memory");
        __builtin_amdgcn_sched_barrier(0);
        const int m0 = rowA0 + wm * 128;
        const int z2 = m0 >> 11, mr = m0 & 2047;
        bf16* CT = (bf16*)C + (long)z2 * 2097152 + (long)(ccol0 + wn * 64 + lane) * 2048 + mr;
        const char* tr = tw + lane * 256;
        const int sw2 = lane & 7;
#pragma unroll
        for (int rb = 0; rb < 16; ++rb) {
            u16x8 v = *(const u16x8*)(tr + 16 * (rb ^ sw2));
            *(u16x8*)(CT + 8 * rb) = v;
        }
    } else {
        const int r0 = rowA0 + wm * WR + ((lane >> 4) << 2);
        const int c0 = ccol0 + wn * 64 + (lane & 15);
        const bool HB = (bias != nullptr);
#pragma unroll
        for (int ni = 0; ni < 4; ++ni) {
            const int c = c0 + ni * 16;
            const float bv = HB ? bias[c] : 0.0f;
#pragma unroll
            for (int mi = 0; mi < MF; ++mi) {
#pragma unroll
                for (int j = 0; j < 4; ++j) {
                    const long r = r0 + mi * 16 + j;
                    storev<OutT>(&C[r * (long)ldc + c], acc[mi][ni][j] * scale + bv);
                }
            }
        }
    }
#undef RAF
#undef RBF
#undef RD_A2
#undef RD_BLO
#undef RD_BHI
#undef MQ1
#undef LA
#undef LB
}

// ---------------- causal row softmax, in place on bf16 scores ----------------
__global__ __launch_bounds__(256) void softmax_causal(bf16* __restrict__ SP, int S) {
    const int i = blockIdx.x;
    bf16* row = SP + ((long)blockIdx.y * S + i) * (long)S;
    const int L = i + 1;
    const int tid = threadIdx.x;
    const int lane = tid & 63, wid = tid >> 6;

    float v[8];
    int nv = 0;
    float m = -3.0e38f;
    for (int j = tid; j < L; j += 256) {
        float x = __bfloat162float(row[j]);
        v[nv++] = x;
        m = fmaxf(m, x);
    }
#pragma unroll
    for (int d = 32; d; d >>= 1) m = fmaxf(m, __shfl_xor(m, d));
    __shared__ float redm[4], reds[4];
    if (lane == 0) redm[wid] = m;
    __syncthreads();
    m = fmaxf(fmaxf(redm[0], redm[1]), fmaxf(redm[2], redm[3]));

    float ssum = 0.f;
    for (int t = 0; t < nv; ++t) { v[t] = __expf(v[t] - m); ssum += v[t]; }
#pragma unroll
    for (int d = 32; d; d >>= 1) ssum += __shfl_xor(ssum, d);
    if (lane == 0) reds[wid] = ssum;
    __syncthreads();
    ssum = reds[0] + reds[1] + reds[2] + reds[3];
    const float inv = 1.0f / ssum;

    nv = 0;
    for (int j = tid; j < L; j += 256) row[j] = __float2bfloat16(v[nv++] * inv);
    const int Lpad = ((i >> 8) + 1) << 8;
    for (int j = L + tid; j < Lpad; j += 256) row[j] = __float2bfloat16(0.0f);
}

extern "C" void kernel_launch(void* const* d_in, const int* in_sizes, int n_in,
                              void* d_out, int out_size, void* d_ws, size_t ws_size,
                              hipStream_t stream) {
    const int B = 4, S = 2048, D = 1024;
    const long MD = (long)B * S * D;
    const float scale = 0.5f / 32.0f;       // TAU / sqrt(D)

    const float* node  = (const float*)d_in[0];
    const float* label = (const float*)d_in[1];
    const float* Wq = (const float*)d_in[2];
    const float* bq = (const float*)d_in[3];
    const float* Wk = (const float*)d_in[4];
    const float* bk = (const float*)d_in[5];
    const float* Wv = (const float*)d_in[6];
    const float* bv = (const float*)d_in[7];
    const float* Wp = (const float*)d_in[8];
    const float* bp = (const float*)d_in[9];
    float* out = (float*)d_out;

    // ws layout: nodeb[0,16M) (dead after KV -> V'T), labelb[16M,32M),
    // Wq[32M) Wk[34M) Wv[36M) Wp[38M) (Wk|Wv stacked for fused KV),
    // Q[40M,56M) K[56M,72M) V[72M,88M) SP[88M,120M)
    char* ws = (char*)d_ws;
    bf16* nodeb  = (bf16*)(ws);
    bf16* VTb    = nodeb;                          // alias (node dead after KV)
    bf16* labelb = (bf16*)(ws + 16777216);
    bf16* Wqb = (bf16*)(ws + 33554432);
    bf16* Wkb = (bf16*)(ws + 35651584);            // Wk|Wv contiguous
    bf16* Wvb = (bf16*)(ws + 37748736);
    bf16* Wpb = (bf16*)(ws + 39845888);
    bf16* Qb  = (bf16*)(ws + 41943040);
    bf16* Kb  = (bf16*)(ws + 58720256);
    bf16* Vb  = (bf16*)(ws + 75497472);
    bf16* SP  = (bf16*)(ws + 92274688);
    if (ws_size < 125829120UL) return;

    dim3 blk(256);

    cvt_pair<<<dim3(512, 2), blk, 0, stream>>>(node, label, (u16x8*)nodeb, (u16x8*)labelb, MD / 8);
    cvt_quad<<<dim3(64, 4), blk, 0, stream>>>(Wq, Wk, Wv, Wp,
        (u16x8*)Wqb, (u16x8*)Wkb, (u16x8*)Wvb, (u16x8*)Wpb, (long)D * D / 8);

    // K|V projections: 256 blocks (exact round); B = stacked Wk|Wv
    gemmX<bf16, 0, 256><<<256, 512, 0, stream>>>(
        nodeb, nullptr, Wkb, nullptr, Kb, Vb, bk, bv,
        1.0f, D, D, D, D, 0, 0, 0);

    // Q | V' = V@Wp^T (transposed write): 128+128 = 256 blocks (exact round)
    gemmX<bf16, 1, 256><<<256, 512, 0, stream>>>(
        labelb, Vb, Wqb, Wpb, Qb, VTb, bq, nullptr,
        1.0f, D, D, D, D, 0, 0, 0);

    // causal scores = (Q @ K^T) * (TAU/sqrt(d)); 36 lower-tri blocks x 4
    gemmX<bf16, 2, 256><<<144, 512, 0, stream>>>(
        Qb, nullptr, Kb, nullptr, SP, nullptr, nullptr, nullptr,
        scale, D, D, S, D, (long)S * D, (long)S * D, (long)S * S);

    // causal softmax in-place (zero-fill to 256 boundary)
    softmax_causal<<<dim3(S, B), blk, 0, stream>>>(SP, S);

    // out = P @ V'^T + bp (fp32), 256x128 tiles, causal k-limit: 256 blocks
    gemmX<float, 3, 128><<<256, 512, 0, stream>>>(
        SP, nullptr, VTb, nullptr, out, nullptr, bp, nullptr,
        1.0f, S, S, D, S, (long)S * S, (long)D * S, (long)S * D);
}

// Round 6
// 188.205 us; speedup vs baseline: 1.0261x; 1.0261x over previous
//
#include <hip/hip_runtime.h>
#include <hip/hip_bf16.h>
#include <stdint.h>

using bf16 = __hip_bfloat16;
typedef __bf16 bf16x8 __attribute__((ext_vector_type(8)));
typedef float f32x4 __attribute__((ext_vector_type(4)));
typedef unsigned short u16x8 __attribute__((ext_vector_type(8)));
typedef unsigned short u16x4 __attribute__((ext_vector_type(4)));

#define AS1 __attribute__((address_space(1)))
#define AS3 __attribute__((address_space(3)))

__device__ inline unsigned short f2b(float f) {
    union { __hip_bfloat16 h; unsigned short u; } cv;
    cv.h = __float2bfloat16(f);
    return cv.u;
}

// ---------------- fp32 -> bf16 converts ----------------
__global__ __launch_bounds__(256) void cvt_pair(const float* __restrict__ a, const float* __restrict__ b,
                                                u16x8* __restrict__ oa, u16x8* __restrict__ ob, long n8) {
    const float* in = blockIdx.y ? b : a;
    u16x8* out = blockIdx.y ? ob : oa;
    long i = (long)blockIdx.x * blockDim.x + threadIdx.x;
    const long stride = (long)gridDim.x * blockDim.x;
    const float4* in4 = (const float4*)in;
    for (; i < n8; i += stride) {
        float4 x = in4[2 * i], y = in4[2 * i + 1];
        u16x8 o;
        o[0] = f2b(x.x); o[1] = f2b(x.y); o[2] = f2b(x.z); o[3] = f2b(x.w);
        o[4] = f2b(y.x); o[5] = f2b(y.y); o[6] = f2b(y.z); o[7] = f2b(y.w);
        out[i] = o;
    }
}

__global__ __launch_bounds__(256) void cvt_quad(const float* __restrict__ a, const float* __restrict__ b,
                                                const float* __restrict__ c, const float* __restrict__ d,
                                                u16x8* __restrict__ oa, u16x8* __restrict__ ob,
                                                u16x8* __restrict__ oc, u16x8* __restrict__ od, long n8) {
    const int y = blockIdx.y;
    const float* in = y == 0 ? a : (y == 1 ? b : (y == 2 ? c : d));
    u16x8* out = y == 0 ? oa : (y == 1 ? ob : (y == 2 ? oc : od));
    long i = (long)blockIdx.x * blockDim.x + threadIdx.x;
    const long stride = (long)gridDim.x * blockDim.x;
    const float4* in4 = (const float4*)in;
    for (; i < n8; i += stride) {
        float4 x = in4[2 * i], z = in4[2 * i + 1];
        u16x8 o;
        o[0] = f2b(x.x); o[1] = f2b(x.y); o[2] = f2b(x.z); o[3] = f2b(x.w);
        o[4] = f2b(z.x); o[5] = f2b(z.y); o[6] = f2b(z.z); o[7] = f2b(z.w);
        out[i] = o;
    }
}

template <typename T> __device__ inline void storev(T* p, float v);
template <> __device__ inline void storev<float>(float* p, float v) { *p = v; }
template <> __device__ inline void storev<bf16>(bf16* p, float v) { *p = __float2bfloat16(v); }

// ================= tiled GEMM: C = A(MxK) * B^T(NxK) =================
// BN=256: 256x256 tile, 8 waves 2Mx4N (per-wave 128x64), 8-phase, LDS 128KB.
// BN=128: 256x128 tile, 8 waves 4Mx2N, 4-phase, LDS 96KB.
// Double-buffered, counted vmcnt across barriers, XOR-swizzled LDS.
// bf16 epilogues go through a per-wave LDS retile -> full-line 16B/lane stores.
// MODE 0: fused K|V projections   MODE 1: fused Q | V'=V@Wp^T (seg1 -> V'T)
// MODE 2: causal scores           MODE 3: PV -> final out (fp32)+bias, k-limit
template <typename OutT, int MODE, int BN>
__global__ __launch_bounds__(512, 2) void gemmX(
    const bf16* __restrict__ A0, const bf16* __restrict__ A1,
    const bf16* __restrict__ B0p, const bf16* __restrict__ B1p,
    OutT* __restrict__ C0, OutT* __restrict__ C1,
    const float* __restrict__ bias0, const float* __restrict__ bias1,
    float scale, int lda, int ldb, int ldc, int Kdim,
    long sA, long sB, long sC)
{
    constexpr int LDSZ = (BN == 256) ? 131072 : 98304;
    constexpr int BUFS = (BN == 256) ? 65536 : 49152;
    __shared__ __align__(16) char lds[LDSZ];

    // ---- block decode with XCD swizzle (all grids %8 == 0)
    const int nwg = gridDim.x;
    const int bid = blockIdx.x;
    const int s = (nwg & 7) ? bid : ((bid & 7) * (nwg >> 3) + (bid >> 3));

    int bm, ccol0, rowB0, seg = 0;
    const bf16 *A, *B;
    OutT* C;
    const float* bias = nullptr;

    if constexpr (MODE == 0) {                 // K|V: 256 = 32bm x 8bn
        bm = s >> 3; const int bnl = s & 7; seg = bnl >> 2;
        A = A0; B = B0p; rowB0 = bnl * 256;
        C = seg ? C1 : C0; bias = seg ? bias1 : bias0;
        ccol0 = (bnl & 3) * 256;
    } else if constexpr (MODE == 1) {          // Q | VWp: 256 = 2seg x 32bm x 4bn
        seg = s >> 7; const int r = s & 127; bm = r >> 2; const int bn = r & 3;
        A = seg ? A1 : A0; B = seg ? B1p : B0p;
        C = seg ? C1 : C0; bias = seg ? nullptr : bias0;
        rowB0 = bn * 256; ccol0 = bn * 256;
    } else if constexpr (MODE == 2) {          // scores: 144 = 4z x 36tri
        const int z = s / 36, f = s % 36;
        int m = 0;
        while ((m + 1) * (m + 2) / 2 <= f) ++m;
        bm = m; const int bn = f - m * (m + 1) / 2;
        A = A0 + (long)z * sA; B = B0p + (long)z * sB; C = C0 + (long)z * sC;
        rowB0 = bn * 256; ccol0 = bn * 256;
    } else {                                   // PV: 256 = 4z x 8bm x 8bn
        const int z = s >> 6, r = s & 63; bm = r >> 3; const int bn = r & 7;
        A = A0 + (long)z * sA; B = B0p + (long)z * sB; C = C0 + (long)z * sC;
        rowB0 = bn * 128; ccol0 = bn * 128; bias = bias0;
    }

    int KT = Kdim >> 6;
    if constexpr (MODE == 3) { const int lim = 4 * (bm + 1); if (lim < KT) KT = lim; }
    const int NIT = KT >> 1;

    const int tid = threadIdx.x;
    const int lane = tid & 63;
    const int w = tid >> 6;
    constexpr int WR = (BN == 256) ? 128 : 64;
    const int wm = (BN == 256) ? (w >> 2) : (w >> 1);
    const int wn = (BN == 256) ? (w & 3) : (w & 1);

    const int rowA0 = bm * 256;

    // ---- staging (linear LDS dest, inverse-swizzled global source)
    const int rr  = tid >> 3;
    const int lch = (tid & 7) ^ (rr & 7);
    const bf16* gAt = A + (long)(rowA0 + rr) * lda + lch * 8;
    const bf16* gBt = B + (long)(rowB0 + rr) * ldb + lch * 8;

#define LA(b) (lds + (b) * BUFS)
#define LB(b) (lds + 32768 + (b) * BUFS)

    auto SG2 = [&](const bf16* g, int ld, char* dst) {
        __builtin_amdgcn_global_load_lds((const AS1 void*)g,
            (AS3 void*)(dst + tid * 16), 16, 0, 0);
        __builtin_amdgcn_global_load_lds((const AS1 void*)(g + (long)64 * ld),
            (AS3 void*)(dst + 8192 + tid * 16), 16, 0, 0);
    };
    auto ST_A = [&](int kt, int half, int b) {
        SG2(gAt + (long)kt * 64 + (long)half * 128 * lda, lda, LA(b) + half * 16384);
    };
    auto ST_B = [&](int kt, int half, int b) {
        SG2(gBt + (long)kt * 64 + (long)half * 128 * ldb, ldb, LB(b) + half * 16384);
    };
    auto ST_B1 = [&](int kt, int b) {            // BN=128 full B tile
        SG2(gBt + (long)kt * 64, ldb, LB(b));
    };

    // ---- swizzled fragment read addressing
    const int abase = (wm * WR + (lane & 15)) * 128;
    const int bbase = (wn * 64 + (lane & 15)) * 128;
    const int cc0 = (((lane >> 4) << 4)) ^ ((lane & 7) << 4);
    const int cc1 = cc0 ^ 64;

#define RAF(b, mh, mi, kk) (*(const bf16x8*)(LA(b) + abase + (mh)*8192 + (mi)*2048 + ((kk) ? cc1 : cc0)))
#define RBF(b, ni, kk)     (*(const bf16x8*)(LB(b) + bbase + (ni)*2048 + ((kk) ? cc1 : cc0)))

    f32x4 acc[(BN == 256) ? 8 : 4][4] = {};
    bf16x8 ar[4][2], blo[2][2], bhi[2][2];

#define RD_A2(b, mh, MI0) { ar[MI0][0] = RAF(b, mh, MI0, 0); ar[MI0][1] = RAF(b, mh, MI0, 1); \
                            ar[(MI0)+1][0] = RAF(b, mh, (MI0)+1, 0); ar[(MI0)+1][1] = RAF(b, mh, (MI0)+1, 1); }
#define RD_BLO(b)   { blo[0][0] = RBF(b, 0, 0); blo[0][1] = RBF(b, 0, 1); blo[1][0] = RBF(b, 1, 0); blo[1][1] = RBF(b, 1, 1); }
#define RD_BHI(b)   { bhi[0][0] = RBF(b, 2, 0); bhi[0][1] = RBF(b, 2, 1); bhi[1][0] = RBF(b, 3, 0); bhi[1][1] = RBF(b, 3, 1); }

#define MQ1(MI, bb, MH, NB) { \
    f32x4 t0_ = acc[(MH)*4 + (MI)][(NB)]; \
    t0_ = __builtin_amdgcn_mfma_f32_16x16x32_bf16(ar[MI][0], bb[0][0], t0_, 0, 0, 0); \
    t0_ = __builtin_amdgcn_mfma_f32_16x16x32_bf16(ar[MI][1], bb[0][1], t0_, 0, 0, 0); \
    acc[(MH)*4 + (MI)][(NB)] = t0_; \
    f32x4 t1_ = acc[(MH)*4 + (MI)][(NB) + 1]; \
    t1_ = __builtin_amdgcn_mfma_f32_16x16x32_bf16(ar[MI][0], bb[1][0], t1_, 0, 0, 0); \
    t1_ = __builtin_amdgcn_mfma_f32_16x16x32_bf16(ar[MI][1], bb[1][1], t1_, 0, 0, 0); \
    acc[(MH)*4 + (MI)][(NB) + 1] = t1_; }

#define WAIT_LGKM0 { asm volatile("s_waitcnt lgkmcnt(0)" ::: "memory"); __builtin_amdgcn_sched_barrier(0); }
#define WAIT_LGKM4 { asm volatile("s_waitcnt lgkmcnt(4)" ::: "memory"); __builtin_amdgcn_sched_barrier(0); }
#define SCHEDB     __builtin_amdgcn_sched_barrier(0)

    auto BAR = [&]() { __builtin_amdgcn_s_barrier(); SCHEDB; };
    auto PRIO1 = [&]() { __builtin_amdgcn_s_setprio(1); };
    auto PRIO0 = [&]() { __builtin_amdgcn_s_setprio(0); };

    if constexpr (BN == 256) {
        // ---- prologue: tile0 full -> buf0, tile1 B -> buf1; retire tile0
        ST_A(0, 0, 0); ST_A(0, 1, 0); ST_B(0, 0, 0); ST_B(0, 1, 0);
        ST_B(1, 0, 1); ST_B(1, 1, 1);
        asm volatile("s_waitcnt vmcnt(4)" ::: "memory");
        BAR();

        for (int i = 0; i < NIT; ++i) {
            const int t0 = 2 * i;
            const bool last = (i == NIT - 1);

            // P1
            RD_BLO(0); RD_A2(0, 0, 0); SCHEDB; RD_A2(0, 0, 2);
            ST_A(t0 + 1, 0, 1);
            BAR(); WAIT_LGKM4; PRIO1();
            MQ1(0, blo, 0, 0); MQ1(1, blo, 0, 0);
            WAIT_LGKM0;
            MQ1(2, blo, 0, 0); MQ1(3, blo, 0, 0);
            PRIO0(); BAR();
            // P2
            RD_BHI(0);
            ST_A(t0 + 1, 1, 1);
            BAR(); WAIT_LGKM0; PRIO1();
            MQ1(0, bhi, 0, 2); MQ1(1, bhi, 0, 2); MQ1(2, bhi, 0, 2); MQ1(3, bhi, 0, 2);
            PRIO0(); BAR();
            // P3
            RD_A2(0, 1, 0); SCHEDB; RD_A2(0, 1, 2);
            if (!last) ST_B(t0 + 2, 0, 0);
            BAR(); WAIT_LGKM4; PRIO1();
            MQ1(0, bhi, 1, 2); MQ1(1, bhi, 1, 2);
            WAIT_LGKM0;
            MQ1(2, bhi, 1, 2); MQ1(3, bhi, 1, 2);
            PRIO0(); BAR();
            // P4
            if (!last) { ST_B(t0 + 2, 1, 0);
                         asm volatile("s_waitcnt vmcnt(4)" ::: "memory"); }
            else       { asm volatile("s_waitcnt vmcnt(0)" ::: "memory"); }
            BAR(); WAIT_LGKM0; PRIO1();
            MQ1(0, blo, 1, 0); MQ1(1, blo, 1, 0); MQ1(2, blo, 1, 0); MQ1(3, blo, 1, 0);
            PRIO0(); BAR();
            // P5
            RD_BLO(1); RD_A2(1, 0, 0); SCHEDB; RD_A2(1, 0, 2);
            if (!last) ST_A(t0 + 2, 0, 0);
            BAR(); WAIT_LGKM4; PRIO1();
            MQ1(0, blo, 0, 0); MQ1(1, blo, 0, 0);
            WAIT_LGKM0;
            MQ1(2, blo, 0, 0); MQ1(3, blo, 0, 0);
            PRIO0(); BAR();
            // P6
            RD_BHI(1);
            if (!last) ST_A(t0 + 2, 1, 0);
            BAR(); WAIT_LGKM0; PRIO1();
            MQ1(0, bhi, 0, 2); MQ1(1, bhi, 0, 2); MQ1(2, bhi, 0, 2); MQ1(3, bhi, 0, 2);
            PRIO0(); BAR();
            // P7
            RD_A2(1, 1, 0); SCHEDB; RD_A2(1, 1, 2);
            if (!last) ST_B(t0 + 3, 0, 1);
            BAR(); WAIT_LGKM4; PRIO1();
            MQ1(0, bhi, 1, 2); MQ1(1, bhi, 1, 2);
            WAIT_LGKM0;
            MQ1(2, bhi, 1, 2); MQ1(3, bhi, 1, 2);
            PRIO0(); BAR();
            // P8
            if (!last) { ST_B(t0 + 3, 1, 1);
                         asm volatile("s_waitcnt vmcnt(4)" ::: "memory"); }
            BAR(); WAIT_LGKM0; PRIO1();
            MQ1(0, blo, 1, 0); MQ1(1, blo, 1, 0); MQ1(2, blo, 1, 0); MQ1(3, blo, 1, 0);
            PRIO0(); BAR();
        }
    } else {
        // ---- BN=128 4-phase. Prologue: tiles 0,1 full; retire tile0.
        ST_A(0, 0, 0); ST_A(0, 1, 0); ST_B1(0, 0);
        ST_A(1, 0, 1); ST_A(1, 1, 1); ST_B1(1, 1);
        asm volatile("s_waitcnt vmcnt(6)" ::: "memory");
        BAR();

        for (int i = 0; i < NIT; ++i) {
            const int t0 = 2 * i;
            const bool last = (i == NIT - 1);

            RD_BLO(0); RD_A2(0, 0, 0); RD_A2(0, 0, 2); SCHEDB; RD_BHI(0);
            BAR(); WAIT_LGKM4; PRIO1();
            MQ1(0, blo, 0, 0); MQ1(1, blo, 0, 0); MQ1(2, blo, 0, 0); MQ1(3, blo, 0, 0);
            PRIO0(); BAR();

            if (!last) { ST_A(t0 + 2, 0, 0); ST_A(t0 + 2, 1, 0);
                         asm volatile("s_waitcnt vmcnt(4)" ::: "memory"); }
            else       { asm volatile("s_waitcnt vmcnt(0)" ::: "memory"); }
            BAR(); WAIT_LGKM0; PRIO1();
            MQ1(0, bhi, 0, 2); MQ1(1, bhi, 0, 2); MQ1(2, bhi, 0, 2); MQ1(3, bhi, 0, 2);
            PRIO0(); BAR();

            RD_BLO(1); RD_A2(1, 0, 0); RD_A2(1, 0, 2); SCHEDB; RD_BHI(1);
            if (!last) ST_B1(t0 + 2, 0);
            BAR(); WAIT_LGKM4; PRIO1();
            MQ1(0, blo, 0, 0); MQ1(1, blo, 0, 0); MQ1(2, blo, 0, 0); MQ1(3, blo, 0, 0);
            PRIO0(); BAR();

            if (!last) { ST_A(t0 + 3, 0, 1); ST_A(t0 + 3, 1, 1); ST_B1(t0 + 3, 1);
                         asm volatile("s_waitcnt vmcnt(6)" ::: "memory"); }
            BAR(); WAIT_LGKM0; PRIO1();
            MQ1(0, bhi, 0, 2); MQ1(1, bhi, 0, 2); MQ1(2, bhi, 0, 2); MQ1(3, bhi, 0, 2);
            PRIO0(); BAR();
        }
    }

    // ==================== epilogues ====================
    if constexpr (BN == 256) {
        char* tw = lds + w * 16384;          // wave-private; safe after final BAR
        if (MODE == 1 && seg == 1) {
            // V'T per batch via per-wave LDS transpose; 16B/lane column stores.
#pragma unroll
            for (int ni = 0; ni < 4; ++ni) {
                const int cl = ni * 16 + (lane & 15);
                const int sw = 8 * (cl & 7);
#pragma unroll
                for (int mi = 0; mi < 8; ++mi) {
                    const int rlb = mi * 16 + ((lane >> 4) << 2);
                    u16x4 o;
                    o[0] = f2b(acc[mi][ni][0]); o[1] = f2b(acc[mi][ni][1]);
                    o[2] = f2b(acc[mi][ni][2]); o[3] = f2b(acc[mi][ni][3]);
                    *(u16x4*)(tw + cl * 256 + 2 * (rlb ^ sw)) = o;
                }
            }
            asm volatile("s_waitcnt lgkmcnt(0)" ::: "memory");
            __builtin_amdgcn_sched_barrier(0);
            const int m0 = rowA0 + wm * 128;
            const int z2 = m0 >> 11, mr = m0 & 2047;
            bf16* CT = (bf16*)C + (long)z2 * 2097152 + (long)(ccol0 + wn * 64 + lane) * 2048 + mr;
            const char* tr = tw + lane * 256;
            const int sw2 = lane & 7;
#pragma unroll
            for (int rb = 0; rb < 16; ++rb) {
                u16x8 v = *(const u16x8*)(tr + 16 * (rb ^ sw2));
                *(u16x8*)(CT + 8 * rb) = v;
            }
        } else {
            // bf16 row-retile: full 16B/lane row-segment stores (no partial lines)
            const int q = lane >> 4, t = lane & 15;
            const int c0 = ccol0 + wn * 64 + t;
#pragma unroll
            for (int mi = 0; mi < 8; ++mi) {
                char* tm = tw + mi * 2048;
#pragma unroll
                for (int ni = 0; ni < 4; ++ni) {
                    const float bv = bias ? bias[c0 + ni * 16] : 0.0f;
                    const int cb = (t + 16 * ni) * 2;
#pragma unroll
                    for (int j = 0; j < 4; ++j) {
                        const int rl = q * 4 + j;
                        *(bf16*)(tm + rl * 128 + (cb ^ ((rl & 7) << 4))) =
                            __float2bfloat16(acc[mi][ni][j] * scale + bv);
                    }
                }
            }
            asm volatile("s_waitcnt lgkmcnt(0)" ::: "memory");
            __builtin_amdgcn_sched_barrier(0);
            const int rr2 = lane >> 2, chb = (lane & 3) * 2;
            const int gr0 = rowA0 + wm * 128;
            bf16* Cb = (bf16*)C;
            const int gcb = ccol0 + wn * 64;
#pragma unroll
            for (int mi = 0; mi < 8; ++mi) {
                const char* tm = tw + mi * 2048;
                const long gr = gr0 + mi * 16 + rr2;
#pragma unroll
                for (int k = 0; k < 2; ++k) {
                    const int chunk = chb + k;
                    u16x8 v = *(const u16x8*)(tm + rr2 * 128 + ((chunk << 4) ^ ((rr2 & 7) << 4)));
                    *(u16x8*)(Cb + gr * (long)ldc + gcb + chunk * 8) = v;
                }
            }
        }
    } else {
        // BN=128 fp32 path (already full-line: 16 lanes x 4B = 64B rows)
        const int r0 = rowA0 + wm * WR + ((lane >> 4) << 2);
        const int c0 = ccol0 + wn * 64 + (lane & 15);
        const bool HB = (bias != nullptr);
#pragma unroll
        for (int ni = 0; ni < 4; ++ni) {
            const int c = c0 + ni * 16;
            const float bv = HB ? bias[c] : 0.0f;
#pragma unroll
            for (int mi = 0; mi < 4; ++mi) {
#pragma unroll
                for (int j = 0; j < 4; ++j) {
                    const long r = r0 + mi * 16 + j;
                    storev<OutT>(&C[r * (long)ldc + c], acc[mi][ni][j] * scale + bv);
                }
            }
        }
    }
#undef RAF
#undef RBF
#undef RD_A2
#undef RD_BLO
#undef RD_BHI
#undef MQ1
#undef LA
#undef LB
}

// ---------------- causal row softmax, in place on bf16 scores ----------------
__global__ __launch_bounds__(256) void softmax_causal(bf16* __restrict__ SP, int S) {
    const int i = blockIdx.x;
    bf16* row = SP + ((long)blockIdx.y * S + i) * (long)S;
    const int L = i + 1;
    const int tid = threadIdx.x;
    const int lane = tid & 63, wid = tid >> 6;

    float v[8];
    int nv = 0;
    float m = -3.0e38f;
    for (int j = tid; j < L; j += 256) {
        float x = __bfloat162float(row[j]);
        v[nv++] = x;
        m = fmaxf(m, x);
    }
#pragma unroll
    for (int d = 32; d; d >>= 1) m = fmaxf(m, __shfl_xor(m, d));
    __shared__ float redm[4], reds[4];
    if (lane == 0) redm[wid] = m;
    __syncthreads();
    m = fmaxf(fmaxf(redm[0], redm[1]), fmaxf(redm[2], redm[3]));

    float ssum = 0.f;
    for (int t = 0; t < nv; ++t) { v[t] = __expf(v[t] - m); ssum += v[t]; }
#pragma unroll
    for (int d = 32; d; d >>= 1) ssum += __shfl_xor(ssum, d);
    if (lane == 0) reds[wid] = ssum;
    __syncthreads();
    ssum = reds[0] + reds[1] + reds[2] + reds[3];
    const float inv = 1.0f / ssum;

    nv = 0;
    for (int j = tid; j < L; j += 256) row[j] = __float2bfloat16(v[nv++] * inv);
    const int Lpad = ((i >> 8) + 1) << 8;
    for (int j = L + tid; j < Lpad; j += 256) row[j] = __float2bfloat16(0.0f);
}

extern "C" void kernel_launch(void* const* d_in, const int* in_sizes, int n_in,
                              void* d_out, int out_size, void* d_ws, size_t ws_size,
                              hipStream_t stream) {
    const int B = 4, S = 2048, D = 1024;
    const long MD = (long)B * S * D;
    const float scale = 0.5f / 32.0f;       // TAU / sqrt(D)

    const float* node  = (const float*)d_in[0];
    const float* label = (const float*)d_in[1];
    const float* Wq = (const float*)d_in[2];
    const float* bq = (const float*)d_in[3];
    const float* Wk = (const float*)d_in[4];
    const float* bk = (const float*)d_in[5];
    const float* Wv = (const float*)d_in[6];
    const float* bv = (const float*)d_in[7];
    const float* Wp = (const float*)d_in[8];
    const float* bp = (const float*)d_in[9];
    float* out = (float*)d_out;

    // ws layout: nodeb[0,16M) (dead after KV -> V'T), labelb[16M,32M),
    // Wq[32M) Wk[34M) Wv[36M) Wp[38M) (Wk|Wv stacked for fused KV),
    // Q[40M,56M) K[56M,72M) V[72M,88M) SP[88M,120M)
    char* ws = (char*)d_ws;
    bf16* nodeb  = (bf16*)(ws);
    bf16* VTb    = nodeb;                          // alias (node dead after KV)
    bf16* labelb = (bf16*)(ws + 16777216);
    bf16* Wqb = (bf16*)(ws + 33554432);
    bf16* Wkb = (bf16*)(ws + 35651584);            // Wk|Wv contiguous
    bf16* Wvb = (bf16*)(ws + 37748736);
    bf16* Wpb = (bf16*)(ws + 39845888);
    bf16* Qb  = (bf16*)(ws + 41943040);
    bf16* Kb  = (bf16*)(ws + 58720256);
    bf16* Vb  = (bf16*)(ws + 75497472);
    bf16* SP  = (bf16*)(ws + 92274688);
    if (ws_size < 125829120UL) return;

    dim3 blk(256);

    cvt_pair<<<dim3(512, 2), blk, 0, stream>>>(node, label, (u16x8*)nodeb, (u16x8*)labelb, MD / 8);
    cvt_quad<<<dim3(64, 4), blk, 0, stream>>>(Wq, Wk, Wv, Wp,
        (u16x8*)Wqb, (u16x8*)Wkb, (u16x8*)Wvb, (u16x8*)Wpb, (long)D * D / 8);

    // K|V projections: 256 blocks (exact round); B = stacked Wk|Wv
    gemmX<bf16, 0, 256><<<256, 512, 0, stream>>>(
        nodeb, nullptr, Wkb, nullptr, Kb, Vb, bk, bv,
        1.0f, D, D, D, D, 0, 0, 0);

    // Q | V' = V@Wp^T (transposed write): 128+128 = 256 blocks (exact round)
    gemmX<bf16, 1, 256><<<256, 512, 0, stream>>>(
        labelb, Vb, Wqb, Wpb, Qb, VTb, bq, nullptr,
        1.0f, D, D, D, D, 0, 0, 0);

    // causal scores = (Q @ K^T) * (TAU/sqrt(d)); 36 lower-tri blocks x 4
    gemmX<bf16, 2, 256><<<144, 512, 0, stream>>>(
        Qb, nullptr, Kb, nullptr, SP, nullptr, nullptr, nullptr,
        scale, D, D, S, D, (long)S * D, (long)S * D, (long)S * S);

    // causal softmax in-place (zero-fill to 256 boundary)
    softmax_causal<<<dim3(S, B), blk, 0, stream>>>(SP, S);

    // out = P @ V'^T + bp (fp32), 256x128 tiles, causal k-limit: 256 blocks
    gemmX<float, 3, 128><<<256, 512, 0, stream>>>(
        SP, nullptr, VTb, nullptr, out, nullptr, bp, nullptr,
        1.0f, S, S, D, S, (long)S * S, (long)D * S, (long)S * D);
}

// Round 7
// 182.921 us; speedup vs baseline: 1.0558x; 1.0289x over previous
//
#include <hip/hip_runtime.h>
#include <hip/hip_bf16.h>
#include <stdint.h>

using bf16 = __hip_bfloat16;
typedef __bf16 bf16x8 __attribute__((ext_vector_type(8)));
typedef float f32x4 __attribute__((ext_vector_type(4)));
typedef unsigned short u16x8 __attribute__((ext_vector_type(8)));
typedef unsigned short u16x4 __attribute__((ext_vector_type(4)));

#define AS1 __attribute__((address_space(1)))
#define AS3 __attribute__((address_space(3)))

__device__ inline unsigned short f2b(float f) {
    union { __hip_bfloat16 h; unsigned short u; } cv;
    cv.h = __float2bfloat16(f);
    return cv.u;
}

// ---------------- fp32 -> bf16 converts ----------------
__global__ __launch_bounds__(256) void cvt_pair(const float* __restrict__ a, const float* __restrict__ b,
                                                u16x8* __restrict__ oa, u16x8* __restrict__ ob, long n8) {
    const float* in = blockIdx.y ? b : a;
    u16x8* out = blockIdx.y ? ob : oa;
    long i = (long)blockIdx.x * blockDim.x + threadIdx.x;
    const long stride = (long)gridDim.x * blockDim.x;
    const float4* in4 = (const float4*)in;
    for (; i < n8; i += stride) {
        float4 x = in4[2 * i], y = in4[2 * i + 1];
        u16x8 o;
        o[0] = f2b(x.x); o[1] = f2b(x.y); o[2] = f2b(x.z); o[3] = f2b(x.w);
        o[4] = f2b(y.x); o[5] = f2b(y.y); o[6] = f2b(y.z); o[7] = f2b(y.w);
        out[i] = o;
    }
}

__global__ __launch_bounds__(256) void cvt_quad(const float* __restrict__ a, const float* __restrict__ b,
                                                const float* __restrict__ c, const float* __restrict__ d,
                                                u16x8* __restrict__ oa, u16x8* __restrict__ ob,
                                                u16x8* __restrict__ oc, u16x8* __restrict__ od, long n8) {
    const int y = blockIdx.y;
    const float* in = y == 0 ? a : (y == 1 ? b : (y == 2 ? c : d));
    u16x8* out = y == 0 ? oa : (y == 1 ? ob : (y == 2 ? oc : od));
    long i = (long)blockIdx.x * blockDim.x + threadIdx.x;
    const long stride = (long)gridDim.x * blockDim.x;
    const float4* in4 = (const float4*)in;
    for (; i < n8; i += stride) {
        float4 x = in4[2 * i], z = in4[2 * i + 1];
        u16x8 o;
        o[0] = f2b(x.x); o[1] = f2b(x.y); o[2] = f2b(x.z); o[3] = f2b(x.w);
        o[4] = f2b(z.x); o[5] = f2b(z.y); o[6] = f2b(z.z); o[7] = f2b(z.w);
        out[i] = o;
    }
}

template <typename T> __device__ inline void storev(T* p, float v);
template <> __device__ inline void storev<float>(float* p, float v) { *p = v; }
template <> __device__ inline void storev<bf16>(bf16* p, float v) { *p = __float2bfloat16(v); }

// ================= tiled GEMM: C = A(MxK) * B^T(NxK) =================
// BN=256: 256x256 tile, 8 waves 2Mx4N (per-wave 128x64), 8-phase with
//   one barrier/phase and frag reads pipelined ONE PHASE AHEAD (reads for
//   phase k+1 issue inside phase k's MFMA region -> LDS overlaps MFMA).
//   lgkmcnt(0) sits BEFORE each barrier so no wave crosses a barrier with
//   LDS reads in flight (stage write-after-read safety).
// BN=128: 256x128 tile, 8 waves 4Mx2N, 4-phase (round-4 structure).
// MODE 0: fused K|V projections   MODE 1: fused Q | V'=V@Wp^T (seg1 -> V'T)
// MODE 2: causal scores           MODE 3: PV -> final out (fp32)+bias, k-limit
template <typename OutT, int MODE, int BN>
__global__ __launch_bounds__(512, 2) void gemmX(
    const bf16* __restrict__ A0, const bf16* __restrict__ A1,
    const bf16* __restrict__ B0p, const bf16* __restrict__ B1p,
    OutT* __restrict__ C0, OutT* __restrict__ C1,
    const float* __restrict__ bias0, const float* __restrict__ bias1,
    float scale, int lda, int ldb, int ldc, int Kdim,
    long sA, long sB, long sC)
{
    constexpr int LDSZ = (BN == 256) ? 131072 : 98304;
    constexpr int BUFS = (BN == 256) ? 65536 : 49152;
    __shared__ __align__(16) char lds[LDSZ];

    // ---- block decode with XCD swizzle (all grids %8 == 0)
    const int nwg = gridDim.x;
    const int bid = blockIdx.x;
    const int s = (nwg & 7) ? bid : ((bid & 7) * (nwg >> 3) + (bid >> 3));

    int bm, ccol0, rowB0, seg = 0;
    const bf16 *A, *B;
    OutT* C;
    const float* bias = nullptr;

    if constexpr (MODE == 0) {                 // K|V: 256 = 32bm x 8bn
        bm = s >> 3; const int bnl = s & 7; seg = bnl >> 2;
        A = A0; B = B0p; rowB0 = bnl * 256;
        C = seg ? C1 : C0; bias = seg ? bias1 : bias0;
        ccol0 = (bnl & 3) * 256;
    } else if constexpr (MODE == 1) {          // Q | VWp: 256 = 2seg x 32bm x 4bn
        seg = s >> 7; const int r = s & 127; bm = r >> 2; const int bn = r & 3;
        A = seg ? A1 : A0; B = seg ? B1p : B0p;
        C = seg ? C1 : C0; bias = seg ? nullptr : bias0;
        rowB0 = bn * 256; ccol0 = bn * 256;
    } else if constexpr (MODE == 2) {          // scores: 144 = 4z x 36tri
        const int z = s / 36, f = s % 36;
        int m = 0;
        while ((m + 1) * (m + 2) / 2 <= f) ++m;
        bm = m; const int bn = f - m * (m + 1) / 2;
        A = A0 + (long)z * sA; B = B0p + (long)z * sB; C = C0 + (long)z * sC;
        rowB0 = bn * 256; ccol0 = bn * 256;
    } else {                                   // PV: 256 = 4z x 8bm x 8bn
        const int z = s >> 6, r = s & 63; bm = r >> 3; const int bn = r & 7;
        A = A0 + (long)z * sA; B = B0p + (long)z * sB; C = C0 + (long)z * sC;
        rowB0 = bn * 128; ccol0 = bn * 128; bias = bias0;
    }

    int KT = Kdim >> 6;
    if constexpr (MODE == 3) { const int lim = 4 * (bm + 1); if (lim < KT) KT = lim; }
    const int NIT = KT >> 1;

    const int tid = threadIdx.x;
    const int lane = tid & 63;
    const int w = tid >> 6;
    constexpr int WR = (BN == 256) ? 128 : 64;
    const int wm = (BN == 256) ? (w >> 2) : (w >> 1);
    const int wn = (BN == 256) ? (w & 3) : (w & 1);

    const int rowA0 = bm * 256;

    // ---- staging (linear LDS dest, inverse-swizzled global source)
    const int rr  = tid >> 3;
    const int lch = (tid & 7) ^ (rr & 7);
    const bf16* gAt = A + (long)(rowA0 + rr) * lda + lch * 8;
    const bf16* gBt = B + (long)(rowB0 + rr) * ldb + lch * 8;

#define LA(b) (lds + (b) * BUFS)
#define LB(b) (lds + 32768 + (b) * BUFS)

    auto SG2 = [&](const bf16* g, int ld, char* dst) {
        __builtin_amdgcn_global_load_lds((const AS1 void*)g,
            (AS3 void*)(dst + tid * 16), 16, 0, 0);
        __builtin_amdgcn_global_load_lds((const AS1 void*)(g + (long)64 * ld),
            (AS3 void*)(dst + 8192 + tid * 16), 16, 0, 0);
    };
    auto ST_A = [&](int kt, int half, int b) {
        SG2(gAt + (long)kt * 64 + (long)half * 128 * lda, lda, LA(b) + half * 16384);
    };
    auto ST_B = [&](int kt, int half, int b) {
        SG2(gBt + (long)kt * 64 + (long)half * 128 * ldb, ldb, LB(b) + half * 16384);
    };
    auto ST_B1 = [&](int kt, int b) {            // BN=128 full B tile
        SG2(gBt + (long)kt * 64, ldb, LB(b));
    };

    // ---- swizzled fragment read addressing
    const int abase = (wm * WR + (lane & 15)) * 128;
    const int bbase = (wn * 64 + (lane & 15)) * 128;
    const int cc0 = (((lane >> 4) << 4)) ^ ((lane & 7) << 4);
    const int cc1 = cc0 ^ 64;

#define RAF(b, mh, mi, kk) (*(const bf16x8*)(LA(b) + abase + (mh)*8192 + (mi)*2048 + ((kk) ? cc1 : cc0)))
#define RBF(b, ni, kk)     (*(const bf16x8*)(LB(b) + bbase + (ni)*2048 + ((kk) ? cc1 : cc0)))

    f32x4 acc[(BN == 256) ? 8 : 4][4] = {};
    bf16x8 ar[4][2], blo[2][2], bhi[2][2];

#define RD_A2(b, mh, MI0) { ar[MI0][0] = RAF(b, mh, MI0, 0); ar[MI0][1] = RAF(b, mh, MI0, 1); \
                            ar[(MI0)+1][0] = RAF(b, mh, (MI0)+1, 0); ar[(MI0)+1][1] = RAF(b, mh, (MI0)+1, 1); }
#define RD_BLO(b)   { blo[0][0] = RBF(b, 0, 0); blo[0][1] = RBF(b, 0, 1); blo[1][0] = RBF(b, 1, 0); blo[1][1] = RBF(b, 1, 1); }
#define RD_BHI(b)   { bhi[0][0] = RBF(b, 2, 0); bhi[0][1] = RBF(b, 2, 1); bhi[1][0] = RBF(b, 3, 0); bhi[1][1] = RBF(b, 3, 1); }

#define MQ1(MI, bb, MH, NB) { \
    f32x4 t0_ = acc[(MH)*4 + (MI)][(NB)]; \
    t0_ = __builtin_amdgcn_mfma_f32_16x16x32_bf16(ar[MI][0], bb[0][0], t0_, 0, 0, 0); \
    t0_ = __builtin_amdgcn_mfma_f32_16x16x32_bf16(ar[MI][1], bb[0][1], t0_, 0, 0, 0); \
    acc[(MH)*4 + (MI)][(NB)] = t0_; \
    f32x4 t1_ = acc[(MH)*4 + (MI)][(NB) + 1]; \
    t1_ = __builtin_amdgcn_mfma_f32_16x16x32_bf16(ar[MI][0], bb[1][0], t1_, 0, 0, 0); \
    t1_ = __builtin_amdgcn_mfma_f32_16x16x32_bf16(ar[MI][1], bb[1][1], t1_, 0, 0, 0); \
    acc[(MH)*4 + (MI)][(NB) + 1] = t1_; }

#define WAIT_LGKM0 { asm volatile("s_waitcnt lgkmcnt(0)" ::: "memory"); __builtin_amdgcn_sched_barrier(0); }
#define WAIT_LGKM4 { asm volatile("s_waitcnt lgkmcnt(4)" ::: "memory"); __builtin_amdgcn_sched_barrier(0); }
#define SCHEDB     __builtin_amdgcn_sched_barrier(0)
// one-barrier phase boundary: drain own LDS reads, then block-wide barrier
#define PRE_SYNC { asm volatile("s_waitcnt lgkmcnt(0)" ::: "memory"); __builtin_amdgcn_sched_barrier(0); \
                   __builtin_amdgcn_s_barrier(); __builtin_amdgcn_sched_barrier(0); }

    auto BAR = [&]() { __builtin_amdgcn_s_barrier(); SCHEDB; };
    auto PRIO1 = [&]() { __builtin_amdgcn_s_setprio(1); };
    auto PRIO0 = [&]() { __builtin_amdgcn_s_setprio(0); };

    if constexpr (BN == 256) {
        // ---- prologue: tile0 -> buf0 (8 loads), B(t1) -> buf1 (4 loads);
        // vmcnt(4) retires tile0. Then pre-issue R(P1) = blo(b0)+armh0(b0).
        ST_A(0, 0, 0); ST_A(0, 1, 0); ST_B(0, 0, 0); ST_B(0, 1, 0);
        ST_B(1, 0, 1); ST_B(1, 1, 1);
        asm volatile("s_waitcnt vmcnt(4)" ::: "memory");
        BAR();
        RD_BLO(0); RD_A2(0, 0, 0); RD_A2(0, 0, 2);

        // Per phase: {stage; [vmcnt]; lgkm(0); barrier; prio1; reads(k+1)+16 MFMA; prio0}
        // Stage-vs-read disjointness and vmcnt ledger verified per round-7 notes.
        for (int i = 0; i < NIT; ++i) {
            const int t0 = 2 * i;
            const bool last = (i == NIT - 1);

            // P1: M = t0 mh0 x blo.  R2 = bhi(b0) (no reg WAR -> overlaps MFMA)
            ST_A(t0 + 1, 0, 1);
            PRE_SYNC; PRIO1();
            RD_BHI(0);
            MQ1(0, blo, 0, 0); MQ1(1, blo, 0, 0); MQ1(2, blo, 0, 0); MQ1(3, blo, 0, 0);
            PRIO0();

            // P2: M = t0 mh0 x bhi.  R3 = ar mh1(b0) (WAR on ar -> after MFMAs)
            ST_A(t0 + 1, 1, 1);
            PRE_SYNC; PRIO1();
            MQ1(0, bhi, 0, 2); MQ1(1, bhi, 0, 2); MQ1(2, bhi, 0, 2); MQ1(3, bhi, 0, 2);
            RD_A2(0, 1, 0); RD_A2(0, 1, 2);
            PRIO0();

            // P3: M = t0 mh1 x bhi.  (no reads)
            if (!last) ST_B(t0 + 2, 0, 0);
            PRE_SYNC; PRIO1();
            MQ1(0, bhi, 1, 2); MQ1(1, bhi, 1, 2); MQ1(2, bhi, 1, 2); MQ1(3, bhi, 1, 2);
            PRIO0();

            // P4: M = t0 mh1 x blo.  R5 = blo(b1)+armh0(b1). vmcnt(4): t0+1 ready.
            if (!last) { ST_B(t0 + 2, 1, 0);
                         asm volatile("s_waitcnt vmcnt(4)" ::: "memory"); }
            else       { asm volatile("s_waitcnt vmcnt(0)" ::: "memory"); }
            PRE_SYNC; PRIO1();
            MQ1(0, blo, 1, 0); MQ1(1, blo, 1, 0); MQ1(2, blo, 1, 0); MQ1(3, blo, 1, 0);
            RD_BLO(1); RD_A2(1, 0, 0); RD_A2(1, 0, 2);
            PRIO0();

            // P5: M = t1 mh0 x blo.  R6 = bhi(b1)
            if (!last) ST_A(t0 + 2, 0, 0);
            PRE_SYNC; PRIO1();
            RD_BHI(1);
            MQ1(0, blo, 0, 0); MQ1(1, blo, 0, 0); MQ1(2, blo, 0, 0); MQ1(3, blo, 0, 0);
            PRIO0();

            // P6: M = t1 mh0 x bhi.  R7 = ar mh1(b1)
            if (!last) ST_A(t0 + 2, 1, 0);
            PRE_SYNC; PRIO1();
            MQ1(0, bhi, 0, 2); MQ1(1, bhi, 0, 2); MQ1(2, bhi, 0, 2); MQ1(3, bhi, 0, 2);
            RD_A2(1, 1, 0); RD_A2(1, 1, 2);
            PRIO0();

            // P7: M = t1 mh1 x bhi.  (no reads)
            if (!last) ST_B(t0 + 3, 0, 1);
            PRE_SYNC; PRIO1();
            MQ1(0, bhi, 1, 2); MQ1(1, bhi, 1, 2); MQ1(2, bhi, 1, 2); MQ1(3, bhi, 1, 2);
            PRIO0();

            // P8: M = t1 mh1 x blo.  R1' = blo(b0')+armh0(b0'). vmcnt(4): t0+2 ready.
            if (!last) { ST_B(t0 + 3, 1, 1);
                         asm volatile("s_waitcnt vmcnt(4)" ::: "memory"); }
            PRE_SYNC; PRIO1();
            MQ1(0, blo, 1, 0); MQ1(1, blo, 1, 0); MQ1(2, blo, 1, 0); MQ1(3, blo, 1, 0);
            if (!last) { RD_BLO(0); RD_A2(0, 0, 0); RD_A2(0, 0, 2); }
            PRIO0();
        }
    } else {
        // ---- BN=128 4-phase (round-4 structure). Prologue: tiles 0,1 full.
        ST_A(0, 0, 0); ST_A(0, 1, 0); ST_B1(0, 0);
        ST_A(1, 0, 1); ST_A(1, 1, 1); ST_B1(1, 1);
        asm volatile("s_waitcnt vmcnt(6)" ::: "memory");
        BAR();

        for (int i = 0; i < NIT; ++i) {
            const int t0 = 2 * i;
            const bool last = (i == NIT - 1);

            RD_BLO(0); RD_A2(0, 0, 0); RD_A2(0, 0, 2); SCHEDB; RD_BHI(0);
            BAR(); WAIT_LGKM4; PRIO1();
            MQ1(0, blo, 0, 0); MQ1(1, blo, 0, 0); MQ1(2, blo, 0, 0); MQ1(3, blo, 0, 0);
            PRIO0(); BAR();

            if (!last) { ST_A(t0 + 2, 0, 0); ST_A(t0 + 2, 1, 0);
                         asm volatile("s_waitcnt vmcnt(4)" ::: "memory"); }
            else       { asm volatile("s_waitcnt vmcnt(0)" ::: "memory"); }
            BAR(); WAIT_LGKM0; PRIO1();
            MQ1(0, bhi, 0, 2); MQ1(1, bhi, 0, 2); MQ1(2, bhi, 0, 2); MQ1(3, bhi, 0, 2);
            PRIO0(); BAR();

            RD_BLO(1); RD_A2(1, 0, 0); RD_A2(1, 0, 2); SCHEDB; RD_BHI(1);
            if (!last) ST_B1(t0 + 2, 0);
            BAR(); WAIT_LGKM4; PRIO1();
            MQ1(0, blo, 0, 0); MQ1(1, blo, 0, 0); MQ1(2, blo, 0, 0); MQ1(3, blo, 0, 0);
            PRIO0(); BAR();

            if (!last) { ST_A(t0 + 3, 0, 1); ST_A(t0 + 3, 1, 1); ST_B1(t0 + 3, 1);
                         asm volatile("s_waitcnt vmcnt(6)" ::: "memory"); }
            BAR(); WAIT_LGKM0; PRIO1();
            MQ1(0, bhi, 0, 2); MQ1(1, bhi, 0, 2); MQ1(2, bhi, 0, 2); MQ1(3, bhi, 0, 2);
            PRIO0(); BAR();
        }
    }

    // ==================== epilogues ====================
    if constexpr (BN == 256) {
        char* tw = lds + w * 16384;          // wave-private; last iter issues no
                                             // LDS reads after its final barrier
        if (MODE == 1 && seg == 1) {
            // V'T per batch via per-wave LDS transpose; 16B/lane column stores.
#pragma unroll
            for (int ni = 0; ni < 4; ++ni) {
                const int cl = ni * 16 + (lane & 15);
                const int sw = 8 * (cl & 7);
#pragma unroll
                for (int mi = 0; mi < 8; ++mi) {
                    const int rlb = mi * 16 + ((lane >> 4) << 2);
                    u16x4 o;
                    o[0] = f2b(acc[mi][ni][0]); o[1] = f2b(acc[mi][ni][1]);
                    o[2] = f2b(acc[mi][ni][2]); o[3] = f2b(acc[mi][ni][3]);
                    *(u16x4*)(tw + cl * 256 + 2 * (rlb ^ sw)) = o;
                }
            }
            asm volatile("s_waitcnt lgkmcnt(0)" ::: "memory");
            __builtin_amdgcn_sched_barrier(0);
            const int m0 = rowA0 + wm * 128;
            const int z2 = m0 >> 11, mr = m0 & 2047;
            bf16* CT = (bf16*)C + (long)z2 * 2097152 + (long)(ccol0 + wn * 64 + lane) * 2048 + mr;
            const char* tr = tw + lane * 256;
            const int sw2 = lane & 7;
#pragma unroll
            for (int rb = 0; rb < 16; ++rb) {
                u16x8 v = *(const u16x8*)(tr + 16 * (rb ^ sw2));
                *(u16x8*)(CT + 8 * rb) = v;
            }
        } else {
            // bf16 row-retile: full 16B/lane row-segment stores (no partial lines)
            const int q = lane >> 4, t = lane & 15;
            const int c0 = ccol0 + wn * 64 + t;
#pragma unroll
            for (int mi = 0; mi < 8; ++mi) {
                char* tm = tw + mi * 2048;
#pragma unroll
                for (int ni = 0; ni < 4; ++ni) {
                    const float bv = bias ? bias[c0 + ni * 16] : 0.0f;
                    const int cb = (t + 16 * ni) * 2;
#pragma unroll
                    for (int j = 0; j < 4; ++j) {
                        const int rl = q * 4 + j;
                        *(bf16*)(tm + rl * 128 + (cb ^ ((rl & 7) << 4))) =
                            __float2bfloat16(acc[mi][ni][j] * scale + bv);
                    }
                }
            }
            asm volatile("s_waitcnt lgkmcnt(0)" ::: "memory");
            __builtin_amdgcn_sched_barrier(0);
            const int rr2 = lane >> 2, chb = (lane & 3) * 2;
            const int gr0 = rowA0 + wm * 128;
            bf16* Cb = (bf16*)C;
            const int gcb = ccol0 + wn * 64;
#pragma unroll
            for (int mi = 0; mi < 8; ++mi) {
                const char* tm = tw + mi * 2048;
                const long gr = gr0 + mi * 16 + rr2;
#pragma unroll
                for (int k = 0; k < 2; ++k) {
                    const int chunk = chb + k;
                    u16x8 v = *(const u16x8*)(tm + rr2 * 128 + ((chunk << 4) ^ ((rr2 & 7) << 4)));
                    *(u16x8*)(Cb + gr * (long)ldc + gcb + chunk * 8) = v;
                }
            }
        }
    } else {
        // BN=128 fp32 path (already full-line: 16 lanes x 4B = 64B rows)
        const int r0 = rowA0 + wm * WR + ((lane >> 4) << 2);
        const int c0 = ccol0 + wn * 64 + (lane & 15);
        const bool HB = (bias != nullptr);
#pragma unroll
        for (int ni = 0; ni < 4; ++ni) {
            const int c = c0 + ni * 16;
            const float bv = HB ? bias[c] : 0.0f;
#pragma unroll
            for (int mi = 0; mi < 4; ++mi) {
#pragma unroll
                for (int j = 0; j < 4; ++j) {
                    const long r = r0 + mi * 16 + j;
                    storev<OutT>(&C[r * (long)ldc + c], acc[mi][ni][j] * scale + bv);
                }
            }
        }
    }
#undef RAF
#undef RBF
#undef RD_A2
#undef RD_BLO
#undef RD_BHI
#undef MQ1
#undef LA
#undef LB
}

// ---------------- causal row softmax, in place on bf16 scores ----------------
__global__ __launch_bounds__(256) void softmax_causal(bf16* __restrict__ SP, int S) {
    const int i = blockIdx.x;
    bf16* row = SP + ((long)blockIdx.y * S + i) * (long)S;
    const int L = i + 1;
    const int tid = threadIdx.x;
    const int lane = tid & 63, wid = tid >> 6;

    float v[8];
    int nv = 0;
    float m = -3.0e38f;
    for (int j = tid; j < L; j += 256) {
        float x = __bfloat162float(row[j]);
        v[nv++] = x;
        m = fmaxf(m, x);
    }
#pragma unroll
    for (int d = 32; d; d >>= 1) m = fmaxf(m, __shfl_xor(m, d));
    __shared__ float redm[4], reds[4];
    if (lane == 0) redm[wid] = m;
    __syncthreads();
    m = fmaxf(fmaxf(redm[0], redm[1]), fmaxf(redm[2], redm[3]));

    float ssum = 0.f;
    for (int t = 0; t < nv; ++t) { v[t] = __expf(v[t] - m); ssum += v[t]; }
#pragma unroll
    for (int d = 32; d; d >>= 1) ssum += __shfl_xor(ssum, d);
    if (lane == 0) reds[wid] = ssum;
    __syncthreads();
    ssum = reds[0] + reds[1] + reds[2] + reds[3];
    const float inv = 1.0f / ssum;

    nv = 0;
    for (int j = tid; j < L; j += 256) row[j] = __float2bfloat16(v[nv++] * inv);
    const int Lpad = ((i >> 8) + 1) << 8;
    for (int j = L + tid; j < Lpad; j += 256) row[j] = __float2bfloat16(0.0f);
}

extern "C" void kernel_launch(void* const* d_in, const int* in_sizes, int n_in,
                              void* d_out, int out_size, void* d_ws, size_t ws_size,
                              hipStream_t stream) {
    const int B = 4, S = 2048, D = 1024;
    const long MD = (long)B * S * D;
    const float scale = 0.5f / 32.0f;       // TAU / sqrt(D)

    const float* node  = (const float*)d_in[0];
    const float* label = (const float*)d_in[1];
    const float* Wq = (const float*)d_in[2];
    const float* bq = (const float*)d_in[3];
    const float* Wk = (const float*)d_in[4];
    const float* bk = (const float*)d_in[5];
    const float* Wv = (const float*)d_in[6];
    const float* bv = (const float*)d_in[7];
    const float* Wp = (const float*)d_in[8];
    const float* bp = (const float*)d_in[9];
    float* out = (float*)d_out;

    // ws layout: nodeb[0,16M) (dead after KV -> V'T), labelb[16M,32M),
    // Wq[32M) Wk[34M) Wv[36M) Wp[38M) (Wk|Wv stacked for fused KV),
    // Q[40M,56M) K[56M,72M) V[72M,88M) SP[88M,120M)
    char* ws = (char*)d_ws;
    bf16* nodeb  = (bf16*)(ws);
    bf16* VTb    = nodeb;                          // alias (node dead after KV)
    bf16* labelb = (bf16*)(ws + 16777216);
    bf16* Wqb = (bf16*)(ws + 33554432);
    bf16* Wkb = (bf16*)(ws + 35651584);            // Wk|Wv contiguous
    bf16* Wvb = (bf16*)(ws + 37748736);
    bf16* Wpb = (bf16*)(ws + 39845888);
    bf16* Qb  = (bf16*)(ws + 41943040);
    bf16* Kb  = (bf16*)(ws + 58720256);
    bf16* Vb  = (bf16*)(ws + 75497472);
    bf16* SP  = (bf16*)(ws + 92274688);
    if (ws_size < 125829120UL) return;

    dim3 blk(256);

    cvt_pair<<<dim3(512, 2), blk, 0, stream>>>(node, label, (u16x8*)nodeb, (u16x8*)labelb, MD / 8);
    cvt_quad<<<dim3(64, 4), blk, 0, stream>>>(Wq, Wk, Wv, Wp,
        (u16x8*)Wqb, (u16x8*)Wkb, (u16x8*)Wvb, (u16x8*)Wpb, (long)D * D / 8);

    // K|V projections: 256 blocks (exact round); B = stacked Wk|Wv
    gemmX<bf16, 0, 256><<<256, 512, 0, stream>>>(
        nodeb, nullptr, Wkb, nullptr, Kb, Vb, bk, bv,
        1.0f, D, D, D, D, 0, 0, 0);

    // Q | V' = V@Wp^T (transposed write): 128+128 = 256 blocks (exact round)
    gemmX<bf16, 1, 256><<<256, 512, 0, stream>>>(
        labelb, Vb, Wqb, Wpb, Qb, VTb, bq, nullptr,
        1.0f, D, D, D, D, 0, 0, 0);

    // causal scores = (Q @ K^T) * (TAU/sqrt(d)); 36 lower-tri blocks x 4
    gemmX<bf16, 2, 256><<<144, 512, 0, stream>>>(
        Qb, nullptr, Kb, nullptr, SP, nullptr, nullptr, nullptr,
        scale, D, D, S, D, (long)S * D, (long)S * D, (long)S * S);

    // causal softmax in-place (zero-fill to 256 boundary)
    softmax_causal<<<dim3(S, B), blk, 0, stream>>>(SP, S);

    // out = P @ V'^T + bp (fp32), 256x128 tiles, causal k-limit: 256 blocks
    gemmX<float, 3, 128><<<256, 512, 0, stream>>>(
        SP, nullptr, VTb, nullptr, out, nullptr, bp, nullptr,
        1.0f, S, S, D, S, (long)S * S, (long)D * S, (long)S * D);
}

// Round 8
// 172.278 us; speedup vs baseline: 1.1210x; 1.0618x over previous
//
#include <hip/hip_runtime.h>
#include <hip/hip_bf16.h>
#include <stdint.h>

using bf16 = __hip_bfloat16;
typedef __bf16 bf16x8 __attribute__((ext_vector_type(8)));
typedef float f32x4 __attribute__((ext_vector_type(4)));
typedef unsigned short u16x8 __attribute__((ext_vector_type(8)));
typedef unsigned short u16x4 __attribute__((ext_vector_type(4)));

#define AS1 __attribute__((address_space(1)))
#define AS3 __attribute__((address_space(3)))

__device__ inline unsigned short f2b(float f) {
    union { __hip_bfloat16 h; unsigned short u; } cv;
    cv.h = __float2bfloat16(f);
    return cv.u;
}

// ---------------- fused fp32 -> bf16 converts (one dispatch) ----------------
__global__ __launch_bounds__(256) void cvt6(
    const float* __restrict__ i0, const float* __restrict__ i1,
    const float* __restrict__ i2, const float* __restrict__ i3,
    const float* __restrict__ i4, const float* __restrict__ i5,
    u16x8* __restrict__ o0, u16x8* __restrict__ o1,
    u16x8* __restrict__ o2, u16x8* __restrict__ o3,
    u16x8* __restrict__ o4, u16x8* __restrict__ o5,
    long nbig, long nsmall)
{
    const int y = blockIdx.y;
    const float* in = y == 0 ? i0 : (y == 1 ? i1 : (y == 2 ? i2 : (y == 3 ? i3 : (y == 4 ? i4 : i5))));
    u16x8* out = y == 0 ? o0 : (y == 1 ? o1 : (y == 2 ? o2 : (y == 3 ? o3 : (y == 4 ? o4 : o5))));
    const long n8 = (y < 2) ? nbig : nsmall;
    long i = (long)blockIdx.x * blockDim.x + threadIdx.x;
    const long stride = (long)gridDim.x * blockDim.x;
    const float4* in4 = (const float4*)in;
    for (; i < n8; i += stride) {
        float4 x = in4[2 * i], z = in4[2 * i + 1];
        u16x8 o;
        o[0] = f2b(x.x); o[1] = f2b(x.y); o[2] = f2b(x.z); o[3] = f2b(x.w);
        o[4] = f2b(z.x); o[5] = f2b(z.y); o[6] = f2b(z.z); o[7] = f2b(z.w);
        out[i] = o;
    }
}

template <typename T> __device__ inline void storev(T* p, float v);
template <> __device__ inline void storev<float>(float* p, float v) { *p = v; }
template <> __device__ inline void storev<bf16>(bf16* p, float v) { *p = __float2bfloat16(v); }

// ================= tiled GEMM: C = A(MxK) * B^T(NxK) =================
// BN=256: 256x256 tile, 8 waves 2Mx4N, 8-phase one-barrier pipelined reads.
// BN=128: 256x128 tile, 8 waves 4Mx2N, 4-phase.
// MODE 0: fused K|V projections   MODE 1: fused Q | V'=V@Wp^T (seg1 -> V'T)
// MODE 2: causal scores -> P' = exp(s*scale) masked, + row partial sums (C1)
// MODE 3: PV -> out = (P' @ V'^T) / rowsum + bias (fp32), causal k-limit;
//         rowsum assembled from partials (B1p) in prologue -> LDS inv table.
template <typename OutT, int MODE, int BN>
__global__ __launch_bounds__(512, 2) void gemmX(
    const bf16* __restrict__ A0, const bf16* __restrict__ A1,
    const bf16* __restrict__ B0p, const bf16* __restrict__ B1p,
    OutT* __restrict__ C0, OutT* __restrict__ C1,
    const float* __restrict__ bias0, const float* __restrict__ bias1,
    float scale, int lda, int ldb, int ldc, int Kdim,
    long sA, long sB, long sC)
{
    constexpr int LDSZ = (BN == 256) ? 131072 : ((MODE == 3) ? 99328 : 98304);
    constexpr int BUFS = (BN == 256) ? 65536 : 49152;
    __shared__ __align__(16) char lds[LDSZ];

    // ---- block decode with XCD swizzle (all grids %8 == 0)
    const int nwg = gridDim.x;
    const int bid = blockIdx.x;
    const int s = (nwg & 7) ? bid : ((bid & 7) * (nwg >> 3) + (bid >> 3));

    int bm, ccol0, rowB0, seg = 0, bn_s = 0, zidx = 0;
    const bf16 *A, *B;
    OutT* C;
    const float* bias = nullptr;

    if constexpr (MODE == 0) {                 // K|V: 256 = 32bm x 8bn
        bm = s >> 3; const int bnl = s & 7; seg = bnl >> 2;
        A = A0; B = B0p; rowB0 = bnl * 256;
        C = seg ? C1 : C0; bias = seg ? bias1 : bias0;
        ccol0 = (bnl & 3) * 256;
    } else if constexpr (MODE == 1) {          // Q | VWp: 256 = 2seg x 32bm x 4bn
        seg = s >> 7; const int r = s & 127; bm = r >> 2; const int bn = r & 3;
        A = seg ? A1 : A0; B = seg ? B1p : B0p;
        C = seg ? C1 : C0; bias = seg ? nullptr : bias0;
        rowB0 = bn * 256; ccol0 = bn * 256;
    } else if constexpr (MODE == 2) {          // scores: 144 = 4z x 36tri
        const int z = s / 36, f = s % 36;
        int m = 0;
        while ((m + 1) * (m + 2) / 2 <= f) ++m;
        bm = m; const int bn = f - m * (m + 1) / 2;
        bn_s = bn; zidx = z;
        A = A0 + (long)z * sA; B = B0p + (long)z * sB; C = C0 + (long)z * sC;
        rowB0 = bn * 256; ccol0 = bn * 256;
    } else {                                   // PV: 256 = 4z x 8bm x 8bn
        const int z = s >> 6, r = s & 63; bm = r >> 3; const int bn = r & 7;
        zidx = z;
        A = A0 + (long)z * sA; B = B0p + (long)z * sB; C = C0 + (long)z * sC;
        rowB0 = bn * 128; ccol0 = bn * 128; bias = bias0;
    }

    int KT = Kdim >> 6;
    if constexpr (MODE == 3) { const int lim = 4 * (bm + 1); if (lim < KT) KT = lim; }
    const int NIT = KT >> 1;

    const int tid = threadIdx.x;
    const int lane = tid & 63;
    const int w = tid >> 6;
    constexpr int WR = (BN == 256) ? 128 : 64;
    const int wm = (BN == 256) ? (w >> 2) : (w >> 1);
    const int wn = (BN == 256) ? (w & 3) : (w & 1);

    const int rowA0 = bm * 256;

    // ---- MODE 3 prologue: assemble row inv-sums into LDS (before staging)
    float* invl = (float*)(lds + 98304);
    if constexpr (MODE == 3) {
        if (tid < 256) {
            const float* part = (const float*)B1p + (((long)zidx * 8 + bm) * 32) * 256 + tid;
            float sum = 0.f;
            const int n4 = 4 * (bm + 1);
            for (int b4 = 0; b4 < n4; ++b4) sum += part[(long)b4 * 256];
            invl[tid] = 1.0f / sum;
        }
        asm volatile("s_waitcnt lgkmcnt(0)" ::: "memory");
        __builtin_amdgcn_sched_barrier(0);
    }

    // ---- staging (linear LDS dest, inverse-swizzled global source)
    const int rr  = tid >> 3;
    const int lch = (tid & 7) ^ (rr & 7);
    const bf16* gAt = A + (long)(rowA0 + rr) * lda + lch * 8;
    const bf16* gBt = B + (long)(rowB0 + rr) * ldb + lch * 8;

#define LA(b) (lds + (b) * BUFS)
#define LB(b) (lds + 32768 + (b) * BUFS)

    auto SG2 = [&](const bf16* g, int ld, char* dst) {
        __builtin_amdgcn_global_load_lds((const AS1 void*)g,
            (AS3 void*)(dst + tid * 16), 16, 0, 0);
        __builtin_amdgcn_global_load_lds((const AS1 void*)(g + (long)64 * ld),
            (AS3 void*)(dst + 8192 + tid * 16), 16, 0, 0);
    };
    auto ST_A = [&](int kt, int half, int b) {
        SG2(gAt + (long)kt * 64 + (long)half * 128 * lda, lda, LA(b) + half * 16384);
    };
    auto ST_B = [&](int kt, int half, int b) {
        SG2(gBt + (long)kt * 64 + (long)half * 128 * ldb, ldb, LB(b) + half * 16384);
    };
    auto ST_B1 = [&](int kt, int b) {            // BN=128 full B tile
        SG2(gBt + (long)kt * 64, ldb, LB(b));
    };

    // ---- swizzled fragment read addressing
    const int abase = (wm * WR + (lane & 15)) * 128;
    const int bbase = (wn * 64 + (lane & 15)) * 128;
    const int cc0 = (((lane >> 4) << 4)) ^ ((lane & 7) << 4);
    const int cc1 = cc0 ^ 64;

#define RAF(b, mh, mi, kk) (*(const bf16x8*)(LA(b) + abase + (mh)*8192 + (mi)*2048 + ((kk) ? cc1 : cc0)))
#define RBF(b, ni, kk)     (*(const bf16x8*)(LB(b) + bbase + (ni)*2048 + ((kk) ? cc1 : cc0)))

    f32x4 acc[(BN == 256) ? 8 : 4][4] = {};
    bf16x8 ar[4][2], blo[2][2], bhi[2][2];

#define RD_A2(b, mh, MI0) { ar[MI0][0] = RAF(b, mh, MI0, 0); ar[MI0][1] = RAF(b, mh, MI0, 1); \
                            ar[(MI0)+1][0] = RAF(b, mh, (MI0)+1, 0); ar[(MI0)+1][1] = RAF(b, mh, (MI0)+1, 1); }
#define RD_BLO(b)   { blo[0][0] = RBF(b, 0, 0); blo[0][1] = RBF(b, 0, 1); blo[1][0] = RBF(b, 1, 0); blo[1][1] = RBF(b, 1, 1); }
#define RD_BHI(b)   { bhi[0][0] = RBF(b, 2, 0); bhi[0][1] = RBF(b, 2, 1); bhi[1][0] = RBF(b, 3, 0); bhi[1][1] = RBF(b, 3, 1); }

#define MQ1(MI, bb, MH, NB) { \
    f32x4 t0_ = acc[(MH)*4 + (MI)][(NB)]; \
    t0_ = __builtin_amdgcn_mfma_f32_16x16x32_bf16(ar[MI][0], bb[0][0], t0_, 0, 0, 0); \
    t0_ = __builtin_amdgcn_mfma_f32_16x16x32_bf16(ar[MI][1], bb[0][1], t0_, 0, 0, 0); \
    acc[(MH)*4 + (MI)][(NB)] = t0_; \
    f32x4 t1_ = acc[(MH)*4 + (MI)][(NB) + 1]; \
    t1_ = __builtin_amdgcn_mfma_f32_16x16x32_bf16(ar[MI][0], bb[1][0], t1_, 0, 0, 0); \
    t1_ = __builtin_amdgcn_mfma_f32_16x16x32_bf16(ar[MI][1], bb[1][1], t1_, 0, 0, 0); \
    acc[(MH)*4 + (MI)][(NB) + 1] = t1_; }

#define WAIT_LGKM0 { asm volatile("s_waitcnt lgkmcnt(0)" ::: "memory"); __builtin_amdgcn_sched_barrier(0); }
#define WAIT_LGKM4 { asm volatile("s_waitcnt lgkmcnt(4)" ::: "memory"); __builtin_amdgcn_sched_barrier(0); }
#define SCHEDB     __builtin_amdgcn_sched_barrier(0)
#define PRE_SYNC { asm volatile("s_waitcnt lgkmcnt(0)" ::: "memory"); __builtin_amdgcn_sched_barrier(0); \
                   __builtin_amdgcn_s_barrier(); __builtin_amdgcn_sched_barrier(0); }

    auto BAR = [&]() { __builtin_amdgcn_s_barrier(); SCHEDB; };
    auto PRIO1 = [&]() { __builtin_amdgcn_s_setprio(1); };
    auto PRIO0 = [&]() { __builtin_amdgcn_s_setprio(0); };

    if constexpr (BN == 256) {
        ST_A(0, 0, 0); ST_A(0, 1, 0); ST_B(0, 0, 0); ST_B(0, 1, 0);
        ST_B(1, 0, 1); ST_B(1, 1, 1);
        asm volatile("s_waitcnt vmcnt(4)" ::: "memory");
        BAR();
        RD_BLO(0); RD_A2(0, 0, 0); RD_A2(0, 0, 2);

        for (int i = 0; i < NIT; ++i) {
            const int t0 = 2 * i;
            const bool last = (i == NIT - 1);

            // P1: M = t0 mh0 x blo.  R2 = bhi(b0)
            ST_A(t0 + 1, 0, 1);
            PRE_SYNC; PRIO1();
            RD_BHI(0);
            MQ1(0, blo, 0, 0); MQ1(1, blo, 0, 0); MQ1(2, blo, 0, 0); MQ1(3, blo, 0, 0);
            PRIO0();

            // P2: M = t0 mh0 x bhi.  R3 = ar mh1(b0)
            ST_A(t0 + 1, 1, 1);
            PRE_SYNC; PRIO1();
            MQ1(0, bhi, 0, 2); MQ1(1, bhi, 0, 2); MQ1(2, bhi, 0, 2); MQ1(3, bhi, 0, 2);
            RD_A2(0, 1, 0); RD_A2(0, 1, 2);
            PRIO0();

            // P3: M = t0 mh1 x bhi.
            if (!last) ST_B(t0 + 2, 0, 0);
            PRE_SYNC; PRIO1();
            MQ1(0, bhi, 1, 2); MQ1(1, bhi, 1, 2); MQ1(2, bhi, 1, 2); MQ1(3, bhi, 1, 2);
            PRIO0();

            // P4: M = t0 mh1 x blo.  R5 = blo(b1)+armh0(b1). vmcnt(4): t0+1 ready.
            if (!last) { ST_B(t0 + 2, 1, 0);
                         asm volatile("s_waitcnt vmcnt(4)" ::: "memory"); }
            else       { asm volatile("s_waitcnt vmcnt(0)" ::: "memory"); }
            PRE_SYNC; PRIO1();
            MQ1(0, blo, 1, 0); MQ1(1, blo, 1, 0); MQ1(2, blo, 1, 0); MQ1(3, blo, 1, 0);
            RD_BLO(1); RD_A2(1, 0, 0); RD_A2(1, 0, 2);
            PRIO0();

            // P5: M = t1 mh0 x blo.  R6 = bhi(b1)
            if (!last) ST_A(t0 + 2, 0, 0);
            PRE_SYNC; PRIO1();
            RD_BHI(1);
            MQ1(0, blo, 0, 0); MQ1(1, blo, 0, 0); MQ1(2, blo, 0, 0); MQ1(3, blo, 0, 0);
            PRIO0();

            // P6: M = t1 mh0 x bhi.  R7 = ar mh1(b1)
            if (!last) ST_A(t0 + 2, 1, 0);
            PRE_SYNC; PRIO1();
            MQ1(0, bhi, 0, 2); MQ1(1, bhi, 0, 2); MQ1(2, bhi, 0, 2); MQ1(3, bhi, 0, 2);
            RD_A2(1, 1, 0); RD_A2(1, 1, 2);
            PRIO0();

            // P7: M = t1 mh1 x bhi.
            if (!last) ST_B(t0 + 3, 0, 1);
            PRE_SYNC; PRIO1();
            MQ1(0, bhi, 1, 2); MQ1(1, bhi, 1, 2); MQ1(2, bhi, 1, 2); MQ1(3, bhi, 1, 2);
            PRIO0();

            // P8: M = t1 mh1 x blo.  R1' = blo(b0')+armh0(b0'). vmcnt(4): t0+2 ready.
            if (!last) { ST_B(t0 + 3, 1, 1);
                         asm volatile("s_waitcnt vmcnt(4)" ::: "memory"); }
            PRE_SYNC; PRIO1();
            MQ1(0, blo, 1, 0); MQ1(1, blo, 1, 0); MQ1(2, blo, 1, 0); MQ1(3, blo, 1, 0);
            if (!last) { RD_BLO(0); RD_A2(0, 0, 0); RD_A2(0, 0, 2); }
            PRIO0();
        }
    } else {
        ST_A(0, 0, 0); ST_A(0, 1, 0); ST_B1(0, 0);
        ST_A(1, 0, 1); ST_A(1, 1, 1); ST_B1(1, 1);
        asm volatile("s_waitcnt vmcnt(6)" ::: "memory");
        BAR();

        for (int i = 0; i < NIT; ++i) {
            const int t0 = 2 * i;
            const bool last = (i == NIT - 1);

            RD_BLO(0); RD_A2(0, 0, 0); RD_A2(0, 0, 2); SCHEDB; RD_BHI(0);
            BAR(); WAIT_LGKM4; PRIO1();
            MQ1(0, blo, 0, 0); MQ1(1, blo, 0, 0); MQ1(2, blo, 0, 0); MQ1(3, blo, 0, 0);
            PRIO0(); BAR();

            if (!last) { ST_A(t0 + 2, 0, 0); ST_A(t0 + 2, 1, 0);
                         asm volatile("s_waitcnt vmcnt(4)" ::: "memory"); }
            else       { asm volatile("s_waitcnt vmcnt(0)" ::: "memory"); }
            BAR(); WAIT_LGKM0; PRIO1();
            MQ1(0, bhi, 0, 2); MQ1(1, bhi, 0, 2); MQ1(2, bhi, 0, 2); MQ1(3, bhi, 0, 2);
            PRIO0(); BAR();

            RD_BLO(1); RD_A2(1, 0, 0); RD_A2(1, 0, 2); SCHEDB; RD_BHI(1);
            if (!last) ST_B1(t0 + 2, 0);
            BAR(); WAIT_LGKM4; PRIO1();
            MQ1(0, blo, 0, 0); MQ1(1, blo, 0, 0); MQ1(2, blo, 0, 0); MQ1(3, blo, 0, 0);
            PRIO0(); BAR();

            if (!last) { ST_A(t0 + 3, 0, 1); ST_A(t0 + 3, 1, 1); ST_B1(t0 + 3, 1);
                         asm volatile("s_waitcnt vmcnt(6)" ::: "memory"); }
            BAR(); WAIT_LGKM0; PRIO1();
            MQ1(0, bhi, 0, 2); MQ1(1, bhi, 0, 2); MQ1(2, bhi, 0, 2); MQ1(3, bhi, 0, 2);
            PRIO0(); BAR();
        }
    }

    // ==================== epilogues ====================
    if constexpr (BN == 256) {
        char* tw = lds + w * 16384;
        if constexpr (MODE == 2) {
            // masked exp transform (bf16-rounded back into acc) + row partial sums
            const int q = lane >> 4, t = lane & 15;
            const bool diag = (bm == bn_s);
#pragma unroll
            for (int mi = 0; mi < 8; ++mi)
#pragma unroll
                for (int ni = 0; ni < 4; ++ni)
#pragma unroll
                    for (int j = 0; j < 4; ++j) {
                        float e = __expf(acc[mi][ni][j] * scale);
                        if (diag) {
                            const int rl = wm * 128 + mi * 16 + q * 4 + j;
                            const int cl = wn * 64 + t + ni * 16;
                            if (cl > rl) e = 0.f;
                        }
                        e = __bfloat162float(__float2bfloat16(e));
                        acc[mi][ni][j] = e;
                    }
            float* part = (float*)C1 + ((((long)zidx * 8 + bm) * 32) + bn_s * 4 + wn) * 256;
#pragma unroll
            for (int mi = 0; mi < 8; ++mi) {
                float rs0 = acc[mi][0][0] + acc[mi][1][0] + acc[mi][2][0] + acc[mi][3][0];
                float rs1 = acc[mi][0][1] + acc[mi][1][1] + acc[mi][2][1] + acc[mi][3][1];
                float rs2 = acc[mi][0][2] + acc[mi][1][2] + acc[mi][2][2] + acc[mi][3][2];
                float rs3 = acc[mi][0][3] + acc[mi][1][3] + acc[mi][2][3] + acc[mi][3][3];
#pragma unroll
                for (int d = 1; d < 16; d <<= 1) {
                    rs0 += __shfl_xor(rs0, d); rs1 += __shfl_xor(rs1, d);
                    rs2 += __shfl_xor(rs2, d); rs3 += __shfl_xor(rs3, d);
                }
                if (t == mi) {
                    float4 o; o.x = rs0; o.y = rs1; o.z = rs2; o.w = rs3;
                    *(float4*)(part + wm * 128 + mi * 16 + q * 4) = o;
                }
            }
        }
        if (MODE == 1 && seg == 1) {
            // V'T per batch via per-wave LDS transpose; 16B/lane column stores.
#pragma unroll
            for (int ni = 0; ni < 4; ++ni) {
                const int cl = ni * 16 + (lane & 15);
                const int sw = 8 * (cl & 7);
#pragma unroll
                for (int mi = 0; mi < 8; ++mi) {
                    const int rlb = mi * 16 + ((lane >> 4) << 2);
                    u16x4 o;
                    o[0] = f2b(acc[mi][ni][0]); o[1] = f2b(acc[mi][ni][1]);
                    o[2] = f2b(acc[mi][ni][2]); o[3] = f2b(acc[mi][ni][3]);
                    *(u16x4*)(tw + cl * 256 + 2 * (rlb ^ sw)) = o;
                }
            }
            asm volatile("s_waitcnt lgkmcnt(0)" ::: "memory");
            __builtin_amdgcn_sched_barrier(0);
            const int m0 = rowA0 + wm * 128;
            const int z2 = m0 >> 11, mr = m0 & 2047;
            bf16* CT = (bf16*)C + (long)z2 * 2097152 + (long)(ccol0 + wn * 64 + lane) * 2048 + mr;
            const char* tr = tw + lane * 256;
            const int sw2 = lane & 7;
#pragma unroll
            for (int rb = 0; rb < 16; ++rb) {
                u16x8 v = *(const u16x8*)(tr + 16 * (rb ^ sw2));
                *(u16x8*)(CT + 8 * rb) = v;
            }
        } else {
            // bf16 row-retile: full 16B/lane row-segment stores
            const float sc2 = (MODE == 2) ? 1.0f : scale;
            const int q = lane >> 4, t = lane & 15;
            const int c0 = ccol0 + wn * 64 + t;
#pragma unroll
            for (int mi = 0; mi < 8; ++mi) {
                char* tm = tw + mi * 2048;
#pragma unroll
                for (int ni = 0; ni < 4; ++ni) {
                    const float bv = bias ? bias[c0 + ni * 16] : 0.0f;
                    const int cb = (t + 16 * ni) * 2;
#pragma unroll
                    for (int j = 0; j < 4; ++j) {
                        const int rl = q * 4 + j;
                        *(bf16*)(tm + rl * 128 + (cb ^ ((rl & 7) << 4))) =
                            __float2bfloat16(acc[mi][ni][j] * sc2 + bv);
                    }
                }
            }
            asm volatile("s_waitcnt lgkmcnt(0)" ::: "memory");
            __builtin_amdgcn_sched_barrier(0);
            const int rr2 = lane >> 2, chb = (lane & 3) * 2;
            const int gr0 = rowA0 + wm * 128;
            bf16* Cb = (bf16*)C;
            const int gcb = ccol0 + wn * 64;
#pragma unroll
            for (int mi = 0; mi < 8; ++mi) {
                const char* tm = tw + mi * 2048;
                const long gr = gr0 + mi * 16 + rr2;
#pragma unroll
                for (int k = 0; k < 2; ++k) {
                    const int chunk = chb + k;
                    u16x8 v = *(const u16x8*)(tm + rr2 * 128 + ((chunk << 4) ^ ((rr2 & 7) << 4)));
                    *(u16x8*)(Cb + gr * (long)ldc + gcb + chunk * 8) = v;
                }
            }
        }
    } else {
        // BN=128 fp32 PV path: scale each row by inv-sum from LDS, add bias
        const int q = lane >> 4;
        const int r0 = rowA0 + wm * WR + (q << 2);
        const int rl0 = wm * WR + (q << 2);
        const int c0 = ccol0 + wn * 64 + (lane & 15);
#pragma unroll
        for (int mi = 0; mi < 4; ++mi) {
#pragma unroll
            for (int j = 0; j < 4; ++j) {
                const int rl = rl0 + mi * 16 + j;
                const float iv = (MODE == 3) ? invl[rl] : scale;
                const long r = r0 + mi * 16 + j;
#pragma unroll
                for (int ni = 0; ni < 4; ++ni) {
                    const int c = c0 + ni * 16;
                    const float bv = bias ? bias[c] : 0.0f;
                    storev<OutT>(&C[r * (long)ldc + c], acc[mi][ni][j] * iv + bv);
                }
            }
        }
    }
#undef RAF
#undef RBF
#undef RD_A2
#undef RD_BLO
#undef RD_BHI
#undef MQ1
#undef LA
#undef LB
}

extern "C" void kernel_launch(void* const* d_in, const int* in_sizes, int n_in,
                              void* d_out, int out_size, void* d_ws, size_t ws_size,
                              hipStream_t stream) {
    const int B = 4, S = 2048, D = 1024;
    const long MD = (long)B * S * D;
    const float scale = 0.5f / 32.0f;       // TAU / sqrt(D)

    const float* node  = (const float*)d_in[0];
    const float* label = (const float*)d_in[1];
    const float* Wq = (const float*)d_in[2];
    const float* bq = (const float*)d_in[3];
    const float* Wk = (const float*)d_in[4];
    const float* bk = (const float*)d_in[5];
    const float* Wv = (const float*)d_in[6];
    const float* bv = (const float*)d_in[7];
    const float* Wp = (const float*)d_in[8];
    const float* bp = (const float*)d_in[9];
    float* out = (float*)d_out;

    // ws layout: nodeb[0,16M) (dead after KV -> V'T), labelb[16M,32M),
    // Wq[32M) Wk[34M) Wv[36M) Wp[38M), Q[40M,56M) K[56M,72M)
    // V[72M,88M) (dead after QVWp -> partial sums 1MB) SP[88M,120M)
    char* ws = (char*)d_ws;
    bf16* nodeb  = (bf16*)(ws);
    bf16* VTb    = nodeb;                          // alias (node dead after KV)
    bf16* labelb = (bf16*)(ws + 16777216);
    bf16* Wqb = (bf16*)(ws + 33554432);
    bf16* Wkb = (bf16*)(ws + 35651584);            // Wk|Wv contiguous
    bf16* Wvb = (bf16*)(ws + 37748736);
    bf16* Wpb = (bf16*)(ws + 39845888);
    bf16* Qb  = (bf16*)(ws + 41943040);
    bf16* Kb  = (bf16*)(ws + 58720256);
    bf16* Vb  = (bf16*)(ws + 75497472);
    float* partial = (float*)(ws + 75497472);      // alias (V dead after QVWp)
    bf16* SP  = (bf16*)(ws + 92274688);
    if (ws_size < 125829120UL) return;

    // fused converts (one dispatch)
    cvt6<<<dim3(512, 6), 256, 0, stream>>>(
        node, label, Wq, Wk, Wv, Wp,
        (u16x8*)nodeb, (u16x8*)labelb, (u16x8*)Wqb, (u16x8*)Wkb, (u16x8*)Wvb, (u16x8*)Wpb,
        MD / 8, (long)D * D / 8);

    // K|V projections: 256 blocks (exact round); B = stacked Wk|Wv
    gemmX<bf16, 0, 256><<<256, 512, 0, stream>>>(
        nodeb, nullptr, Wkb, nullptr, Kb, Vb, bk, bv,
        1.0f, D, D, D, D, 0, 0, 0);

    // Q | V' = V@Wp^T (transposed write): 128+128 = 256 blocks (exact round)
    gemmX<bf16, 1, 256><<<256, 512, 0, stream>>>(
        labelb, Vb, Wqb, Wpb, Qb, VTb, bq, nullptr,
        1.0f, D, D, D, D, 0, 0, 0);

    // causal P' = exp((Q @ K^T)*scale) masked + row partial sums -> partial
    gemmX<bf16, 2, 256><<<144, 512, 0, stream>>>(
        Qb, nullptr, Kb, nullptr, SP, (bf16*)partial, nullptr, nullptr,
        scale, D, D, S, D, (long)S * D, (long)S * D, (long)S * S);

    // out = (P' @ V'^T) / rowsum + bp (fp32), causal k-limit: 256 blocks
    gemmX<float, 3, 128><<<256, 512, 0, stream>>>(
        SP, nullptr, VTb, (const bf16*)partial, out, nullptr, bp, nullptr,
        1.0f, S, S, D, S, (long)S * S, (long)D * S, (long)S * D);
}

// Round 9
// 153.409 us; speedup vs baseline: 1.2589x; 1.1230x over previous
//
#include <hip/hip_runtime.h>
#include <hip/hip_bf16.h>
#include <stdint.h>

using bf16 = __hip_bfloat16;
typedef __bf16 bf16x8 __attribute__((ext_vector_type(8)));
typedef float f32x4 __attribute__((ext_vector_type(4)));
typedef unsigned short u16x8 __attribute__((ext_vector_type(8)));
typedef unsigned short u16x4 __attribute__((ext_vector_type(4)));

#define AS1 __attribute__((address_space(1)))
#define AS3 __attribute__((address_space(3)))

__device__ inline unsigned short f2b(float f) {
    union { __hip_bfloat16 h; unsigned short u; } cv;
    cv.h = __float2bfloat16(f);
    return cv.u;
}

// ---------------- fused fp32 -> bf16 converts (one dispatch) ----------------
__global__ __launch_bounds__(256) void cvt6(
    const float* __restrict__ i0, const float* __restrict__ i1,
    const float* __restrict__ i2, const float* __restrict__ i3,
    const float* __restrict__ i4, const float* __restrict__ i5,
    u16x8* __restrict__ o0, u16x8* __restrict__ o1,
    u16x8* __restrict__ o2, u16x8* __restrict__ o3,
    u16x8* __restrict__ o4, u16x8* __restrict__ o5,
    long nbig, long nsmall)
{
    const int y = blockIdx.y;
    const float* in = y == 0 ? i0 : (y == 1 ? i1 : (y == 2 ? i2 : (y == 3 ? i3 : (y == 4 ? i4 : i5))));
    u16x8* out = y == 0 ? o0 : (y == 1 ? o1 : (y == 2 ? o2 : (y == 3 ? o3 : (y == 4 ? o4 : o5))));
    const long n8 = (y < 2) ? nbig : nsmall;
    long i = (long)blockIdx.x * blockDim.x + threadIdx.x;
    const long stride = (long)gridDim.x * blockDim.x;
    const float4* in4 = (const float4*)in;
    for (; i < n8; i += stride) {
        float4 x = in4[2 * i], z = in4[2 * i + 1];
        u16x8 o;
        o[0] = f2b(x.x); o[1] = f2b(x.y); o[2] = f2b(x.z); o[3] = f2b(x.w);
        o[4] = f2b(z.x); o[5] = f2b(z.y); o[6] = f2b(z.z); o[7] = f2b(z.w);
        out[i] = o;
    }
}

template <typename T> __device__ inline void storev(T* p, float v);
template <> __device__ inline void storev<float>(float* p, float v) { *p = v; }
template <> __device__ inline void storev<bf16>(bf16* p, float v) { *p = __float2bfloat16(v); }

// ================= tiled GEMM: C = A(MxK) * B^T(NxK), BN=256 =================
// 256x256 tile, 8 waves 2Mx4N, 8-phase one-barrier pipelined reads.
// MODE 0: fused K|V projections   MODE 1: fused Q | V'=V@Wp^T (seg1 -> V'T)
// MODE 2: causal scores -> P' = exp(s*scale) masked, + row partial sums (C1)
template <typename OutT, int MODE>
__global__ __launch_bounds__(512, 2) void gemmX(
    const bf16* __restrict__ A0, const bf16* __restrict__ A1,
    const bf16* __restrict__ B0p, const bf16* __restrict__ B1p,
    OutT* __restrict__ C0, OutT* __restrict__ C1,
    const float* __restrict__ bias0, const float* __restrict__ bias1,
    float scale, int lda, int ldb, int ldc, int Kdim,
    long sA, long sB, long sC)
{
    __shared__ __align__(16) char lds[131072];

    const int nwg = gridDim.x;
    const int bid = blockIdx.x;
    const int s = (nwg & 7) ? bid : ((bid & 7) * (nwg >> 3) + (bid >> 3));

    int bm, ccol0, rowB0, seg = 0, bn_s = 0, zidx = 0;
    const bf16 *A, *B;
    OutT* C;
    const float* bias = nullptr;

    if constexpr (MODE == 0) {                 // K|V: 256 = 32bm x 8bn
        bm = s >> 3; const int bnl = s & 7; seg = bnl >> 2;
        A = A0; B = B0p; rowB0 = bnl * 256;
        C = seg ? C1 : C0; bias = seg ? bias1 : bias0;
        ccol0 = (bnl & 3) * 256;
    } else if constexpr (MODE == 1) {          // Q | VWp: 256 = 2seg x 32bm x 4bn
        seg = s >> 7; const int r = s & 127; bm = r >> 2; const int bn = r & 3;
        A = seg ? A1 : A0; B = seg ? B1p : B0p;
        C = seg ? C1 : C0; bias = seg ? nullptr : bias0;
        rowB0 = bn * 256; ccol0 = bn * 256;
    } else {                                   // scores: 144 = 4z x 36tri
        const int z = s / 36, f = s % 36;
        int m = 0;
        while ((m + 1) * (m + 2) / 2 <= f) ++m;
        bm = m; const int bn = f - m * (m + 1) / 2;
        bn_s = bn; zidx = z;
        A = A0 + (long)z * sA; B = B0p + (long)z * sB; C = C0 + (long)z * sC;
        rowB0 = bn * 256; ccol0 = bn * 256;
    }

    const int KT = Kdim >> 6;
    const int NIT = KT >> 1;

    const int tid = threadIdx.x;
    const int lane = tid & 63;
    const int w = tid >> 6;
    const int wm = w >> 2;
    const int wn = w & 3;

    const int rowA0 = bm * 256;

    const int rr  = tid >> 3;
    const int lch = (tid & 7) ^ (rr & 7);
    const bf16* gAt = A + (long)(rowA0 + rr) * lda + lch * 8;
    const bf16* gBt = B + (long)(rowB0 + rr) * ldb + lch * 8;

#define LA(b) (lds + (b) * 65536)
#define LB(b) (lds + 32768 + (b) * 65536)

    auto SG2 = [&](const bf16* g, int ld, char* dst) {
        __builtin_amdgcn_global_load_lds((const AS1 void*)g,
            (AS3 void*)(dst + tid * 16), 16, 0, 0);
        __builtin_amdgcn_global_load_lds((const AS1 void*)(g + (long)64 * ld),
            (AS3 void*)(dst + 8192 + tid * 16), 16, 0, 0);
    };
    auto ST_A = [&](int kt, int half, int b) {
        SG2(gAt + (long)kt * 64 + (long)half * 128 * lda, lda, LA(b) + half * 16384);
    };
    auto ST_B = [&](int kt, int half, int b) {
        SG2(gBt + (long)kt * 64 + (long)half * 128 * ldb, ldb, LB(b) + half * 16384);
    };

    const int abase = (wm * 128 + (lane & 15)) * 128;
    const int bbase = (wn * 64 + (lane & 15)) * 128;
    const int cc0 = (((lane >> 4) << 4)) ^ ((lane & 7) << 4);
    const int cc1 = cc0 ^ 64;

#define RAF(b, mh, mi, kk) (*(const bf16x8*)(LA(b) + abase + (mh)*8192 + (mi)*2048 + ((kk) ? cc1 : cc0)))
#define RBF(b, ni, kk)     (*(const bf16x8*)(LB(b) + bbase + (ni)*2048 + ((kk) ? cc1 : cc0)))

    f32x4 acc[8][4] = {};
    bf16x8 ar[4][2], blo[2][2], bhi[2][2];

#define RD_A2(b, mh, MI0) { ar[MI0][0] = RAF(b, mh, MI0, 0); ar[MI0][1] = RAF(b, mh, MI0, 1); \
                            ar[(MI0)+1][0] = RAF(b, mh, (MI0)+1, 0); ar[(MI0)+1][1] = RAF(b, mh, (MI0)+1, 1); }
#define RD_BLO(b)   { blo[0][0] = RBF(b, 0, 0); blo[0][1] = RBF(b, 0, 1); blo[1][0] = RBF(b, 1, 0); blo[1][1] = RBF(b, 1, 1); }
#define RD_BHI(b)   { bhi[0][0] = RBF(b, 2, 0); bhi[0][1] = RBF(b, 2, 1); bhi[1][0] = RBF(b, 3, 0); bhi[1][1] = RBF(b, 3, 1); }

#define MQ1(MI, bb, MH, NB) { \
    f32x4 t0_ = acc[(MH)*4 + (MI)][(NB)]; \
    t0_ = __builtin_amdgcn_mfma_f32_16x16x32_bf16(ar[MI][0], bb[0][0], t0_, 0, 0, 0); \
    t0_ = __builtin_amdgcn_mfma_f32_16x16x32_bf16(ar[MI][1], bb[0][1], t0_, 0, 0, 0); \
    acc[(MH)*4 + (MI)][(NB)] = t0_; \
    f32x4 t1_ = acc[(MH)*4 + (MI)][(NB) + 1]; \
    t1_ = __builtin_amdgcn_mfma_f32_16x16x32_bf16(ar[MI][0], bb[1][0], t1_, 0, 0, 0); \
    t1_ = __builtin_amdgcn_mfma_f32_16x16x32_bf16(ar[MI][1], bb[1][1], t1_, 0, 0, 0); \
    acc[(MH)*4 + (MI)][(NB) + 1] = t1_; }

#define SCHEDB     __builtin_amdgcn_sched_barrier(0)
#define PRE_SYNC { asm volatile("s_waitcnt lgkmcnt(0)" ::: "memory"); __builtin_amdgcn_sched_barrier(0); \
                   __builtin_amdgcn_s_barrier(); __builtin_amdgcn_sched_barrier(0); }

    auto BAR = [&]() { __builtin_amdgcn_s_barrier(); SCHEDB; };
    auto PRIO1 = [&]() { __builtin_amdgcn_s_setprio(1); };
    auto PRIO0 = [&]() { __builtin_amdgcn_s_setprio(0); };

    ST_A(0, 0, 0); ST_A(0, 1, 0); ST_B(0, 0, 0); ST_B(0, 1, 0);
    ST_B(1, 0, 1); ST_B(1, 1, 1);
    asm volatile("s_waitcnt vmcnt(4)" ::: "memory");
    BAR();
    RD_BLO(0); RD_A2(0, 0, 0); RD_A2(0, 0, 2);

    for (int i = 0; i < NIT; ++i) {
        const int t0 = 2 * i;
        const bool last = (i == NIT - 1);

        // P1: M = t0 mh0 x blo.  R2 = bhi(b0)
        ST_A(t0 + 1, 0, 1);
        PRE_SYNC; PRIO1();
        RD_BHI(0);
        MQ1(0, blo, 0, 0); MQ1(1, blo, 0, 0); MQ1(2, blo, 0, 0); MQ1(3, blo, 0, 0);
        PRIO0();

        // P2: M = t0 mh0 x bhi.  R3 = ar mh1(b0)
        ST_A(t0 + 1, 1, 1);
        PRE_SYNC; PRIO1();
        MQ1(0, bhi, 0, 2); MQ1(1, bhi, 0, 2); MQ1(2, bhi, 0, 2); MQ1(3, bhi, 0, 2);
        RD_A2(0, 1, 0); RD_A2(0, 1, 2);
        PRIO0();

        // P3: M = t0 mh1 x bhi.
        if (!last) ST_B(t0 + 2, 0, 0);
        PRE_SYNC; PRIO1();
        MQ1(0, bhi, 1, 2); MQ1(1, bhi, 1, 2); MQ1(2, bhi, 1, 2); MQ1(3, bhi, 1, 2);
        PRIO0();

        // P4: M = t0 mh1 x blo.  R5 = blo(b1)+armh0(b1). vmcnt(4): t0+1 ready.
        if (!last) { ST_B(t0 + 2, 1, 0);
                     asm volatile("s_waitcnt vmcnt(4)" ::: "memory"); }
        else       { asm volatile("s_waitcnt vmcnt(0)" ::: "memory"); }
        PRE_SYNC; PRIO1();
        MQ1(0, blo, 1, 0); MQ1(1, blo, 1, 0); MQ1(2, blo, 1, 0); MQ1(3, blo, 1, 0);
        RD_BLO(1); RD_A2(1, 0, 0); RD_A2(1, 0, 2);
        PRIO0();

        // P5: M = t1 mh0 x blo.  R6 = bhi(b1)
        if (!last) ST_A(t0 + 2, 0, 0);
        PRE_SYNC; PRIO1();
        RD_BHI(1);
        MQ1(0, blo, 0, 0); MQ1(1, blo, 0, 0); MQ1(2, blo, 0, 0); MQ1(3, blo, 0, 0);
        PRIO0();

        // P6: M = t1 mh0 x bhi.  R7 = ar mh1(b1)
        if (!last) ST_A(t0 + 2, 1, 0);
        PRE_SYNC; PRIO1();
        MQ1(0, bhi, 0, 2); MQ1(1, bhi, 0, 2); MQ1(2, bhi, 0, 2); MQ1(3, bhi, 0, 2);
        RD_A2(1, 1, 0); RD_A2(1, 1, 2);
        PRIO0();

        // P7: M = t1 mh1 x bhi.
        if (!last) ST_B(t0 + 3, 0, 1);
        PRE_SYNC; PRIO1();
        MQ1(0, bhi, 1, 2); MQ1(1, bhi, 1, 2); MQ1(2, bhi, 1, 2); MQ1(3, bhi, 1, 2);
        PRIO0();

        // P8: M = t1 mh1 x blo.  R1' next iter. vmcnt(4): t0+2 ready.
        if (!last) { ST_B(t0 + 3, 1, 1);
                     asm volatile("s_waitcnt vmcnt(4)" ::: "memory"); }
        PRE_SYNC; PRIO1();
        MQ1(0, blo, 1, 0); MQ1(1, blo, 1, 0); MQ1(2, blo, 1, 0); MQ1(3, blo, 1, 0);
        if (!last) { RD_BLO(0); RD_A2(0, 0, 0); RD_A2(0, 0, 2); }
        PRIO0();
    }

    // ==================== epilogues ====================
    char* tw = lds + w * 16384;
    if constexpr (MODE == 2) {
        // masked exp transform (bf16-rounded into acc) + row partial sums
        const int q = lane >> 4, t = lane & 15;
        const bool diag = (bm == bn_s);
#pragma unroll
        for (int mi = 0; mi < 8; ++mi)
#pragma unroll
            for (int ni = 0; ni < 4; ++ni)
#pragma unroll
                for (int j = 0; j < 4; ++j) {
                    float e = __expf(acc[mi][ni][j] * scale);
                    if (diag) {
                        const int rl = wm * 128 + mi * 16 + q * 4 + j;
                        const int cl = wn * 64 + t + ni * 16;
                        if (cl > rl) e = 0.f;
                    }
                    e = __bfloat162float(__float2bfloat16(e));
                    acc[mi][ni][j] = e;
                }
        float* part = (float*)C1 + ((((long)zidx * 8 + bm) * 32) + bn_s * 4 + wn) * 256;
#pragma unroll
        for (int mi = 0; mi < 8; ++mi) {
            float rs0 = acc[mi][0][0] + acc[mi][1][0] + acc[mi][2][0] + acc[mi][3][0];
            float rs1 = acc[mi][0][1] + acc[mi][1][1] + acc[mi][2][1] + acc[mi][3][1];
            float rs2 = acc[mi][0][2] + acc[mi][1][2] + acc[mi][2][2] + acc[mi][3][2];
            float rs3 = acc[mi][0][3] + acc[mi][1][3] + acc[mi][2][3] + acc[mi][3][3];
#pragma unroll
            for (int d = 1; d < 16; d <<= 1) {
                rs0 += __shfl_xor(rs0, d); rs1 += __shfl_xor(rs1, d);
                rs2 += __shfl_xor(rs2, d); rs3 += __shfl_xor(rs3, d);
            }
            if (t == mi) {
                float4 o; o.x = rs0; o.y = rs1; o.z = rs2; o.w = rs3;
                *(float4*)(part + wm * 128 + mi * 16 + q * 4) = o;
            }
        }
    }
    if (MODE == 1 && seg == 1) {
        // V'T per batch via per-wave LDS transpose; 16B/lane column stores.
#pragma unroll
        for (int ni = 0; ni < 4; ++ni) {
            const int cl = ni * 16 + (lane & 15);
            const int sw = 8 * (cl & 7);
#pragma unroll
            for (int mi = 0; mi < 8; ++mi) {
                const int rlb = mi * 16 + ((lane >> 4) << 2);
                u16x4 o;
                o[0] = f2b(acc[mi][ni][0]); o[1] = f2b(acc[mi][ni][1]);
                o[2] = f2b(acc[mi][ni][2]); o[3] = f2b(acc[mi][ni][3]);
                *(u16x4*)(tw + cl * 256 + 2 * (rlb ^ sw)) = o;
            }
        }
        asm volatile("s_waitcnt lgkmcnt(0)" ::: "memory");
        __builtin_amdgcn_sched_barrier(0);
        const int m0 = rowA0 + wm * 128;
        const int z2 = m0 >> 11, mr = m0 & 2047;
        bf16* CT = (bf16*)C + (long)z2 * 2097152 + (long)(ccol0 + wn * 64 + lane) * 2048 + mr;
        const char* tr = tw + lane * 256;
        const int sw2 = lane & 7;
#pragma unroll
        for (int rb = 0; rb < 16; ++rb) {
            u16x8 v = *(const u16x8*)(tr + 16 * (rb ^ sw2));
            *(u16x8*)(CT + 8 * rb) = v;
        }
    } else {
        // bf16 row-retile: full 16B/lane row-segment stores
        const float sc2 = (MODE == 2) ? 1.0f : scale;
        const int q = lane >> 4, t = lane & 15;
        const int c0 = ccol0 + wn * 64 + t;
#pragma unroll
        for (int mi = 0; mi < 8; ++mi) {
            char* tm = tw + mi * 2048;
#pragma unroll
            for (int ni = 0; ni < 4; ++ni) {
                const float bv = bias ? bias[c0 + ni * 16] : 0.0f;
                const int cb = (t + 16 * ni) * 2;
#pragma unroll
                for (int j = 0; j < 4; ++j) {
                    const int rl = q * 4 + j;
                    *(bf16*)(tm + rl * 128 + (cb ^ ((rl & 7) << 4))) =
                        __float2bfloat16(acc[mi][ni][j] * sc2 + bv);
                }
            }
        }
        asm volatile("s_waitcnt lgkmcnt(0)" ::: "memory");
        __builtin_amdgcn_sched_barrier(0);
        const int rr2 = lane >> 2, chb = (lane & 3) * 2;
        const int gr0 = rowA0 + wm * 128;
        bf16* Cb = (bf16*)C;
        const int gcb = ccol0 + wn * 64;
#pragma unroll
        for (int mi = 0; mi < 8; ++mi) {
            const char* tm = tw + mi * 2048;
            const long gr = gr0 + mi * 16 + rr2;
#pragma unroll
            for (int k = 0; k < 2; ++k) {
                const int chunk = chb + k;
                u16x8 v = *(const u16x8*)(tm + rr2 * 128 + ((chunk << 4) ^ ((rr2 & 7) << 4)));
                *(u16x8*)(Cb + gr * (long)ldc + gcb + chunk * 8) = v;
            }
        }
    }
#undef RAF
#undef RBF
#undef RD_A2
#undef RD_BLO
#undef RD_BHI
#undef MQ1
#undef LA
#undef LB
}

// ============ balanced causal PV: out = (P' @ V'^T)/rowsum + bias ============
// Pair row-blocks (128 rows) i and 15-i: every block does exactly 34 k-tiles.
// 8 waves 2Mx4N (per-wave 64x32), 3-buffer rotation, 1 k-tile/phase,
// stage t+2 during phase t, counted vmcnt, reads pipelined one phase ahead.
__global__ __launch_bounds__(512, 2) void pv_bal(
    const bf16* __restrict__ P, const bf16* __restrict__ VT,
    const float* __restrict__ part, float* __restrict__ out,
    const float* __restrict__ bias)
{
    __shared__ __align__(16) char lds[99328];  // 3 x 32KB bufs + 1KB inv
    float* invl = (float*)(lds + 98304);

    const int nwg = gridDim.x;
    const int bid = blockIdx.x;
    const int s = (bid & 7) * (nwg >> 3) + (bid >> 3);
    const int z = s >> 6, r = s & 63;
    const int pr = r >> 3, bn = r & 7;
    const int bmA = pr, bmB = 15 - pr;

    const bf16* Pz = P + (long)z * 2048 * 2048;
    const bf16* Vz = VT + (long)z * 1024 * 2048;

    const int tid = threadIdx.x;
    const int lane = tid & 63;
    const int w = tid >> 6;
    const int wm = w >> 2, wn = w & 3;
    const int rr = tid >> 3;
    const int lch = (tid & 7) ^ (rr & 7);

    // inv tables for both sub-tiles (issued first so vmcnt(4) drains them too)
    if (tid < 256) {
        const int half = tid >> 7, rloc = tid & 127;
        const int grow = (half ? bmB : bmA) * 128 + rloc;
        const int b256 = grow >> 8, rin = grow & 255;
        const float* pp = part + (((long)z * 8 + b256) * 32) * 256 + rin;
        const int n4 = 4 * (b256 + 1);
        float s0 = 0.f, s1 = 0.f, s2 = 0.f, s3 = 0.f;
        int b4 = 0;
        for (; b4 + 4 <= n4; b4 += 4) {
            s0 += pp[(long)b4 * 256];       s1 += pp[(long)(b4 + 1) * 256];
            s2 += pp[(long)(b4 + 2) * 256]; s3 += pp[(long)(b4 + 3) * 256];
        }
        for (; b4 < n4; ++b4) s0 += pp[(long)b4 * 256];
        invl[tid] = 1.0f / ((s0 + s1) + (s2 + s3));
    }

    const bf16* gBt = Vz + (long)(bn * 128 + rr) * 2048 + lch * 8;
    const bf16* gAtA = Pz + (long)(bmA * 128 + rr) * 2048 + lch * 8;
    const bf16* gAtB = Pz + (long)(bmB * 128 + rr) * 2048 + lch * 8;

    auto SG2 = [&](const bf16* g, char* dst) {
        __builtin_amdgcn_global_load_lds((const AS1 void*)g,
            (AS3 void*)(dst + tid * 16), 16, 0, 0);
        __builtin_amdgcn_global_load_lds((const AS1 void*)(g + (long)64 * 2048),
            (AS3 void*)(dst + 8192 + tid * 16), 16, 0, 0);
    };
    auto ST = [&](const bf16* gAt, int kt, int b) {
        SG2(gAt + (long)kt * 64, lds + b * 32768);
        SG2(gBt + (long)kt * 64, lds + b * 32768 + 16384);
    };

    const int abase0 = (wm * 64 + (lane & 15)) * 128;
    const int bbase0 = 16384 + (wn * 32 + (lane & 15)) * 128;
    const int cc0 = ((lane >> 4) << 4) ^ ((lane & 7) << 4);
    const int cc1 = cc0 ^ 64;

    f32x4 acc[4][2];
    bf16x8 ar[4][2], br[2][2];

    auto RDF = [&](int t) {
        const char* base = lds + (t % 3) * 32768;
#pragma unroll
        for (int mi = 0; mi < 4; ++mi) {
            ar[mi][0] = *(const bf16x8*)(base + abase0 + mi * 2048 + cc0);
            ar[mi][1] = *(const bf16x8*)(base + abase0 + mi * 2048 + cc1);
        }
#pragma unroll
        for (int ni = 0; ni < 2; ++ni) {
            br[ni][0] = *(const bf16x8*)(base + bbase0 + ni * 2048 + cc0);
            br[ni][1] = *(const bf16x8*)(base + bbase0 + ni * 2048 + cc1);
        }
    };
    auto MFMA16 = [&]() {
#pragma unroll
        for (int mi = 0; mi < 4; ++mi)
#pragma unroll
            for (int ni = 0; ni < 2; ++ni) {
                f32x4 t_ = acc[mi][ni];
                t_ = __builtin_amdgcn_mfma_f32_16x16x32_bf16(ar[mi][0], br[ni][0], t_, 0, 0, 0);
                t_ = __builtin_amdgcn_mfma_f32_16x16x32_bf16(ar[mi][1], br[ni][1], t_, 0, 0, 0);
                acc[mi][ni] = t_;
            }
    };
    auto ZERO = [&]() {
#pragma unroll
        for (int mi = 0; mi < 4; ++mi)
#pragma unroll
            for (int ni = 0; ni < 2; ++ni) acc[mi][ni] = f32x4{0.f, 0.f, 0.f, 0.f};
    };
    auto tile_pass = [&](const bf16* gAt, int KT) {
        // entry: t0,t1 staged; t0 retired by all waves; barrier done
        RDF(0);
        for (int t = 0; t < KT; ++t) {
            if (t + 2 < KT) {
                ST(gAt, t + 2, (t + 2) % 3);
                asm volatile("s_waitcnt vmcnt(4)" ::: "memory");
            } else if (t + 1 < KT) {
                asm volatile("s_waitcnt vmcnt(0)" ::: "memory");
            }
            asm volatile("s_waitcnt lgkmcnt(0)" ::: "memory");
            __builtin_amdgcn_sched_barrier(0);
            __builtin_amdgcn_s_barrier();
            __builtin_amdgcn_sched_barrier(0);
            __builtin_amdgcn_s_setprio(1);
            MFMA16();
            if (t + 1 < KT) RDF(t + 1);
            __builtin_amdgcn_s_setprio(0);
        }
    };
    auto epi = [&](int bm, int invoff) {
        const int q = lane >> 4, t16 = lane & 15;
        const int c0 = bn * 128 + wn * 32 + t16;
        float* op = out + ((long)z * 2048 + (long)bm * 128) * 1024;
#pragma unroll
        for (int mi = 0; mi < 4; ++mi)
#pragma unroll
            for (int j = 0; j < 4; ++j) {
                const int rl = wm * 64 + mi * 16 + q * 4 + j;
                const float iv = invl[invoff + rl];
#pragma unroll
                for (int ni = 0; ni < 2; ++ni) {
                    const int c = c0 + ni * 16;
                    op[(long)rl * 1024 + c] = acc[mi][ni][j] * iv + bias[c];
                }
            }
    };

    const int KTA = 2 * (bmA + 1), KTB = 2 * (bmB + 1);

    // ---- tile A
    ST(gAtA, 0, 0); ST(gAtA, 1, 1);
    asm volatile("s_waitcnt vmcnt(4)" ::: "memory");
    __builtin_amdgcn_s_barrier();
    __builtin_amdgcn_sched_barrier(0);
    ZERO();
    tile_pass(gAtA, KTA);

    // ---- tile B prologue hidden under tile A epilogue
    ST(gAtB, 0, 0); ST(gAtB, 1, 1);
    epi(bmA, 0);
    asm volatile("s_waitcnt vmcnt(0)" ::: "memory");
    __builtin_amdgcn_s_barrier();
    __builtin_amdgcn_sched_barrier(0);
    ZERO();
    tile_pass(gAtB, KTB);
    epi(bmB, 128);
}

extern "C" void kernel_launch(void* const* d_in, const int* in_sizes, int n_in,
                              void* d_out, int out_size, void* d_ws, size_t ws_size,
                              hipStream_t stream) {
    const int B = 4, S = 2048, D = 1024;
    const long MD = (long)B * S * D;
    const float scale = 0.5f / 32.0f;       // TAU / sqrt(D)

    const float* node  = (const float*)d_in[0];
    const float* label = (const float*)d_in[1];
    const float* Wq = (const float*)d_in[2];
    const float* bq = (const float*)d_in[3];
    const float* Wk = (const float*)d_in[4];
    const float* bk = (const float*)d_in[5];
    const float* Wv = (const float*)d_in[6];
    const float* bv = (const float*)d_in[7];
    const float* Wp = (const float*)d_in[8];
    const float* bp = (const float*)d_in[9];
    float* out = (float*)d_out;

    // ws layout: nodeb[0,16M) (dead after KV -> V'T), labelb[16M,32M),
    // Wq[32M) Wk[34M) Wv[36M) Wp[38M), Q[40M,56M) K[56M,72M)
    // V[72M,88M) (dead after QVWp -> partial sums 1MB) SP[88M,120M)
    char* ws = (char*)d_ws;
    bf16* nodeb  = (bf16*)(ws);
    bf16* VTb    = nodeb;                          // alias (node dead after KV)
    bf16* labelb = (bf16*)(ws + 16777216);
    bf16* Wqb = (bf16*)(ws + 33554432);
    bf16* Wkb = (bf16*)(ws + 35651584);            // Wk|Wv contiguous
    bf16* Wvb = (bf16*)(ws + 37748736);
    bf16* Wpb = (bf16*)(ws + 39845888);
    bf16* Qb  = (bf16*)(ws + 41943040);
    bf16* Kb  = (bf16*)(ws + 58720256);
    bf16* Vb  = (bf16*)(ws + 75497472);
    float* partial = (float*)(ws + 75497472);      // alias (V dead after QVWp)
    bf16* SP  = (bf16*)(ws + 92274688);
    if (ws_size < 125829120UL) return;

    // fused converts (one dispatch)
    cvt6<<<dim3(512, 6), 256, 0, stream>>>(
        node, label, Wq, Wk, Wv, Wp,
        (u16x8*)nodeb, (u16x8*)labelb, (u16x8*)Wqb, (u16x8*)Wkb, (u16x8*)Wvb, (u16x8*)Wpb,
        MD / 8, (long)D * D / 8);

    // K|V projections: 256 blocks (exact round); B = stacked Wk|Wv
    gemmX<bf16, 0><<<256, 512, 0, stream>>>(
        nodeb, nullptr, Wkb, nullptr, Kb, Vb, bk, bv,
        1.0f, D, D, D, D, 0, 0, 0);

    // Q | V' = V@Wp^T (transposed write): 128+128 = 256 blocks
    gemmX<bf16, 1><<<256, 512, 0, stream>>>(
        labelb, Vb, Wqb, Wpb, Qb, VTb, bq, nullptr,
        1.0f, D, D, D, D, 0, 0, 0);

    // causal P' = exp((Q @ K^T)*scale) masked + row partial sums -> partial
    gemmX<bf16, 2><<<144, 512, 0, stream>>>(
        Qb, nullptr, Kb, (bf16*)nullptr, SP, (bf16*)partial, nullptr, nullptr,
        scale, D, D, S, D, (long)S * D, (long)S * D, (long)S * S);

    // out = (P' @ V'^T) / rowsum + bp (fp32), balanced pair grid: 256 blocks
    pv_bal<<<256, 512, 0, stream>>>(SP, VTb, partial, out, bp);
}